// Round 3
// baseline (21978.880 us; speedup 1.0000x reference)
//
#include <hip/hip_runtime.h>
#include <hip/hip_bf16.h>

#define N_NODES 100000
#define N_EDGES 3200000
#define DIM 256
#define HID 128
#define NCLS 5

__device__ __forceinline__ float bf2f(unsigned short u) {
    union { unsigned int i; float f; } v; v.i = ((unsigned int)u) << 16; return v.f;
}
__device__ __forceinline__ unsigned short f2bf(float f) {
    union { float f; unsigned int i; } v; v.f = f;
    unsigned int x = v.i;
    return (unsigned short)((x + 0x7FFFu + ((x >> 16) & 1u)) >> 16);
}

// ---------------- degree / norm ----------------
__global__ void k_deg_init(float* deg) {
    int i = blockIdx.x * 256 + threadIdx.x;
    if (i < N_NODES) deg[i] = 1.0f;   // self-loop
}
__global__ void k_deg_count(const int* __restrict__ dst, float* __restrict__ deg) {
    int e = blockIdx.x * 256 + threadIdx.x;
    if (e < N_EDGES) atomicAdd(&deg[dst[e]], 1.0f);
}
__global__ void k_dinv(float* deg) {
    int i = blockIdx.x * 256 + threadIdx.x;
    if (i < N_NODES) deg[i] = rsqrtf(deg[i]);
}

// ---------------- tiled GEMM: C[m,n] = sum_k A[m,k]*W[n,k] (+bias[n]) ----------------
// A: MxK fp32 row-major; W: NoutxK fp32 row-major; Cout: bf16 (internal buffer)
__global__ __launch_bounds__(256) void k_gemm_nt(const float* __restrict__ A,
        const float* __restrict__ W, const float* __restrict__ bias,
        unsigned short* __restrict__ Cout, int M, int Nout, int K)
{
    const int BM = 64, BN = 64, BK = 16;
    __shared__ float As[BK][BM];
    __shared__ float Ws[BK][BN];
    int tx = threadIdx.x, ty = threadIdx.y;
    int tid = ty * 16 + tx;
    int m0 = blockIdx.x * BM, n0 = blockIdx.y * BN;
    int arow = tid >> 2;          // 0..63
    int acol = (tid & 3) * 4;     // 0,4,8,12
    float acc[4][4] = {};
    for (int k0 = 0; k0 < K; k0 += BK) {
        int m = m0 + arow;
        #pragma unroll
        for (int j = 0; j < 4; ++j)
            As[acol + j][arow] = (m < M) ? A[(size_t)m * K + k0 + acol + j] : 0.0f;
        int n = n0 + arow;
        #pragma unroll
        for (int j = 0; j < 4; ++j)
            Ws[acol + j][arow] = (n < Nout) ? W[(size_t)n * K + k0 + acol + j] : 0.0f;
        __syncthreads();
        #pragma unroll
        for (int kk = 0; kk < BK; ++kk) {
            float a[4], b[4];
            #pragma unroll
            for (int i = 0; i < 4; ++i) a[i] = As[kk][ty * 4 + i];
            #pragma unroll
            for (int j = 0; j < 4; ++j) b[j] = Ws[kk][tx * 4 + j];
            #pragma unroll
            for (int i = 0; i < 4; ++i)
                #pragma unroll
                for (int j = 0; j < 4; ++j)
                    acc[i][j] += a[i] * b[j];
        }
        __syncthreads();
    }
    #pragma unroll
    for (int i = 0; i < 4; ++i) {
        int m = m0 + ty * 4 + i;
        if (m >= M) continue;
        #pragma unroll
        for (int j = 0; j < 4; ++j) {
            int n = n0 + tx * 4 + j;
            if (n >= Nout) continue;
            float v = acc[i][j] + (bias ? bias[n] : 0.0f);
            Cout[(size_t)m * Nout + n] = f2bf(v);
        }
    }
}

// ---------------- aggregate init: agg[n,o] = b[o] + dinv[n]^2 * h[n,o] ----------------
__global__ __launch_bounds__(256) void k_agg_init(const unsigned short* __restrict__ h,
        const float* __restrict__ dinv, const float* __restrict__ bias,
        float* __restrict__ agg)
{
    int idx = blockIdx.x * 256 + threadIdx.x;    // over N*DIM/4
    if (idx >= N_NODES * (DIM / 4)) return;
    int i4 = idx * 4;
    int node = i4 >> 8;      // / DIM
    int o = i4 & (DIM - 1);
    float dv = dinv[node];
    float dv2 = dv * dv;
    ushort4 u = *(const ushort4*)(h + i4);
    float4 r;
    r.x = bias[o + 0] + dv2 * bf2f(u.x);
    r.y = bias[o + 1] + dv2 * bf2f(u.y);
    r.z = bias[o + 2] + dv2 * bf2f(u.z);
    r.w = bias[o + 3] + dv2 * bf2f(u.w);
    *(float4*)(agg + i4) = r;
}

// ---------------- edge scatter: one wave per edge ----------------
__global__ __launch_bounds__(256) void k_scatter(const unsigned short* __restrict__ h,
        const int* __restrict__ src, const int* __restrict__ dst,
        const float* __restrict__ dinv, float* __restrict__ agg)
{
    int gt = blockIdx.x * 256 + threadIdx.x;
    int e = gt >> 6;
    int lane = threadIdx.x & 63;
    if (e >= N_EDGES) return;
    int s = src[e], d = dst[e];
    float nrm = dinv[s] * dinv[d];
    ushort4 u = *(const ushort4*)(h + (size_t)s * DIM + lane * 4);
    float* ap = agg + (size_t)d * DIM + lane * 4;
    atomicAdd(ap + 0, nrm * bf2f(u.x));
    atomicAdd(ap + 1, nrm * bf2f(u.y));
    atomicAdd(ap + 2, nrm * bf2f(u.z));
    atomicAdd(ap + 3, nrm * bf2f(u.w));
}

// ---------------- MLP layer 2: out[n,c] = sum_k Hin[n,k]*W[c,k] + b[c]; wave per node ----------------
__global__ __launch_bounds__(256) void k_mlp2(const unsigned short* __restrict__ Hin,
        const float* __restrict__ W, const float* __restrict__ b,
        float* __restrict__ out)
{
    int gt = blockIdx.x * 256 + threadIdx.x;
    int nid = gt >> 6;
    int lane = threadIdx.x & 63;
    if (nid >= N_NODES) return;
    float h0 = bf2f(Hin[(size_t)nid * HID + lane]);
    float h1 = bf2f(Hin[(size_t)nid * HID + 64 + lane]);
    #pragma unroll
    for (int c = 0; c < NCLS; ++c) {
        float p = h0 * W[c * HID + lane] + h1 * W[c * HID + 64 + lane];
        #pragma unroll
        for (int off = 32; off > 0; off >>= 1) p += __shfl_down(p, off);
        if (lane == 0) out[nid * NCLS + c] = p + b[c];
    }
}

extern "C" void kernel_launch(void* const* d_in, const int* in_sizes, int n_in,
                              void* d_out, int out_size, void* d_ws, size_t ws_size,
                              hipStream_t stream)
{
    const float* x   = (const float*)d_in[0];
    const int*   ei  = (const int*)d_in[1];
    const float* W1  = (const float*)d_in[2];
    const float* b1  = (const float*)d_in[3];
    const float* W2  = (const float*)d_in[4];
    const float* b2  = (const float*)d_in[5];
    const float* Wm1 = (const float*)d_in[6];
    const float* bm1 = (const float*)d_in[7];
    const float* Wm2 = (const float*)d_in[8];
    const float* bm2 = (const float*)d_in[9];
    float* out = (float*)d_out;
    const int* src = ei;
    const int* dst = ei + N_EDGES;

    // workspace layout (256B-aligned):
    //   [0, 400000)                      : deg -> dinv (fp32, N)
    //   [1<<19, +102400000)              : agg  (fp32, N*DIM)
    //   [1<<19 + 102400000, +51200000)   : hbuf (bf16, N*DIM)  -- ~154 MB total
    char* ws = (char*)d_ws;
    float* dinv = (float*)ws;
    float* agg  = (float*)(ws + (1 << 19));
    unsigned short* hbuf = (unsigned short*)(ws + (1 << 19) + (size_t)N_NODES * DIM * 4);

    // degrees + symmetric norm
    k_deg_init<<<(N_NODES + 255) / 256, 256, 0, stream>>>(dinv);
    k_deg_count<<<(N_EDGES + 255) / 256, 256, 0, stream>>>(dst, dinv);
    k_dinv<<<(N_NODES + 255) / 256, 256, 0, stream>>>(dinv);

    dim3 blk(16, 16);
    dim3 grid_d((N_NODES + 63) / 64, DIM / 64);
    dim3 grid_h((N_NODES + 63) / 64, HID / 64);

    // GCN layer 1: h = x@W1^T ; agg = b1 + norm-scatter(h)
    k_gemm_nt<<<grid_d, blk, 0, stream>>>(x, W1, nullptr, hbuf, N_NODES, DIM, DIM);
    k_agg_init<<<(N_NODES * (DIM / 4) + 255) / 256, 256, 0, stream>>>(hbuf, dinv, b1, agg);
    k_scatter<<<(N_EDGES * 64) / 256, 256, 0, stream>>>(hbuf, src, dst, dinv, agg);

    // GCN layer 2
    k_gemm_nt<<<grid_d, blk, 0, stream>>>(agg, W2, nullptr, hbuf, N_NODES, DIM, DIM);
    k_agg_init<<<(N_NODES * (DIM / 4) + 255) / 256, 256, 0, stream>>>(hbuf, dinv, b2, agg);
    k_scatter<<<(N_EDGES * 64) / 256, 256, 0, stream>>>(hbuf, src, dst, dinv, agg);

    // MLP head
    k_gemm_nt<<<grid_h, blk, 0, stream>>>(agg, Wm1, bm1, hbuf, N_NODES, HID, DIM);
    k_mlp2<<<(N_NODES * 64) / 256, 256, 0, stream>>>(hbuf, Wm2, bm2, out);
}

// Round 4
// 1993.071 us; speedup vs baseline: 11.0276x; 11.0276x over previous
//
#include <hip/hip_runtime.h>

#define N_NODES 100000
#define N_EDGES 3200000
#define DIM 256
#define HID 128
#define NCLS 5

__device__ __forceinline__ float bf2f(unsigned short u) {
    union { unsigned int i; float f; } v; v.i = ((unsigned int)u) << 16; return v.f;
}
__device__ __forceinline__ unsigned short f2bf(float f) {
    union { float f; unsigned int i; } v; v.f = f;
    unsigned int x = v.i;
    return (unsigned short)((x + 0x7FFFu + ((x >> 16) & 1u)) >> 16);
}
__device__ __forceinline__ float cvtA(unsigned short v) { return bf2f(v); }
__device__ __forceinline__ float cvtA(float v) { return v; }

// ---------------- CSR build ----------------
__global__ void k_zero(int* p, int n) {
    int i = blockIdx.x * 256 + threadIdx.x;
    if (i < n) p[i] = 0;
}
__global__ void k_hist(const int* __restrict__ dst, int* __restrict__ counts) {
    int e = blockIdx.x * 256 + threadIdx.x;
    if (e < N_EDGES) atomicAdd(&counts[dst[e]], 1);
}
__global__ void k_dinv(const int* __restrict__ counts, float* __restrict__ dinv) {
    int i = blockIdx.x * 256 + threadIdx.x;
    if (i < N_NODES) dinv[i] = rsqrtf((float)(counts[i] + 1));   // +1 self-loop
}
// single-block exclusive scan of counts -> rowptr, also seeds cursor
__global__ __launch_bounds__(256) void k_scan(const int* __restrict__ counts,
        int* __restrict__ rowptr, int* __restrict__ cursor)
{
    __shared__ int sdata[256];
    __shared__ int s_base;
    int tid = threadIdx.x;
    if (tid == 0) s_base = 0;
    __syncthreads();
    for (int base = 0; base < N_NODES; base += 256) {
        int i = base + tid;
        int v = (i < N_NODES) ? counts[i] : 0;
        sdata[tid] = v;
        __syncthreads();
        #pragma unroll
        for (int off = 1; off < 256; off <<= 1) {
            int t = (tid >= off) ? sdata[tid - off] : 0;
            __syncthreads();
            sdata[tid] += t;
            __syncthreads();
        }
        int excl = sdata[tid] - v;
        if (i < N_NODES) { int rp = s_base + excl; rowptr[i] = rp; cursor[i] = rp; }
        int total = sdata[255];
        __syncthreads();
        if (tid == 0) s_base += total;
        __syncthreads();
    }
    if (tid == 0) rowptr[N_NODES] = s_base;
}
__global__ void k_bucket(const int* __restrict__ src, const int* __restrict__ dst,
        int* __restrict__ cursor, int* __restrict__ esrc)
{
    int e = blockIdx.x * 256 + threadIdx.x;
    if (e < N_EDGES) {
        int pos = atomicAdd(&cursor[dst[e]], 1);
        esrc[pos] = src[e];
    }
}

// ---------------- tiled GEMM: C[m,n] = sum_k A[m,k]*W[n,k] (+bias[n]); Cout bf16 ----------------
template<typename TA>
__global__ __launch_bounds__(256) void k_gemm_nt(const TA* __restrict__ A,
        const float* __restrict__ W, const float* __restrict__ bias,
        unsigned short* __restrict__ Cout, int M, int Nout, int K)
{
    const int BM = 64, BN = 64, BK = 16;
    __shared__ float As[BK][BM];
    __shared__ float Ws[BK][BN];
    int tx = threadIdx.x, ty = threadIdx.y;
    int tid = ty * 16 + tx;
    int m0 = blockIdx.x * BM, n0 = blockIdx.y * BN;
    int arow = tid >> 2;          // 0..63
    int acol = (tid & 3) * 4;     // 0,4,8,12
    float acc[4][4] = {};
    for (int k0 = 0; k0 < K; k0 += BK) {
        int m = m0 + arow;
        #pragma unroll
        for (int j = 0; j < 4; ++j)
            As[acol + j][arow] = (m < M) ? cvtA(A[(size_t)m * K + k0 + acol + j]) : 0.0f;
        int n = n0 + arow;
        #pragma unroll
        for (int j = 0; j < 4; ++j)
            Ws[acol + j][arow] = (n < Nout) ? W[(size_t)n * K + k0 + acol + j] : 0.0f;
        __syncthreads();
        #pragma unroll
        for (int kk = 0; kk < BK; ++kk) {
            float a[4], b[4];
            #pragma unroll
            for (int i = 0; i < 4; ++i) a[i] = As[kk][ty * 4 + i];
            #pragma unroll
            for (int j = 0; j < 4; ++j) b[j] = Ws[kk][tx * 4 + j];
            #pragma unroll
            for (int i = 0; i < 4; ++i)
                #pragma unroll
                for (int j = 0; j < 4; ++j)
                    acc[i][j] += a[i] * b[j];
        }
        __syncthreads();
    }
    #pragma unroll
    for (int i = 0; i < 4; ++i) {
        int m = m0 + ty * 4 + i;
        if (m >= M) continue;
        #pragma unroll
        for (int j = 0; j < 4; ++j) {
            int n = n0 + tx * 4 + j;
            if (n >= Nout) continue;
            float v = acc[i][j] + (bias ? bias[n] : 0.0f);
            Cout[(size_t)m * Nout + n] = f2bf(v);
        }
    }
}

// ---------------- CSR gather: one wave per node, lane holds 4 features ----------------
// agg[d,:] = bias + dinv[d]^2*h[d,:] + sum_{s in N(d)} dinv[s]*dinv[d]*h[s,:]
__global__ __launch_bounds__(256) void k_gather(const unsigned short* __restrict__ h,
        const int* __restrict__ rowptr, const int* __restrict__ esrc,
        const float* __restrict__ dinv, const float* __restrict__ bias,
        unsigned short* __restrict__ agg)
{
    int d = (blockIdx.x * 256 + threadIdx.x) >> 6;
    int lane4 = (threadIdx.x & 63) * 4;
    if (d >= N_NODES) return;
    float dv = dinv[d];
    int r0 = rowptr[d], r1 = rowptr[d + 1];

    // self-loop + bias
    float a0, a1, a2, a3;
    {
        ushort4 u = *(const ushort4*)(h + (size_t)d * DIM + lane4);
        float4 b4 = *(const float4*)(bias + lane4);
        float nn = dv * dv;
        a0 = b4.x + nn * bf2f(u.x);
        a1 = b4.y + nn * bf2f(u.y);
        a2 = b4.z + nn * bf2f(u.z);
        a3 = b4.w + nn * bf2f(u.w);
    }
    int j = r0;
    for (; j + 3 < r1; j += 4) {
        int s0 = esrc[j], s1 = esrc[j + 1], s2 = esrc[j + 2], s3 = esrc[j + 3];
        float n0 = dinv[s0] * dv, n1 = dinv[s1] * dv, n2 = dinv[s2] * dv, n3 = dinv[s3] * dv;
        ushort4 u0 = *(const ushort4*)(h + (size_t)s0 * DIM + lane4);
        ushort4 u1 = *(const ushort4*)(h + (size_t)s1 * DIM + lane4);
        ushort4 u2 = *(const ushort4*)(h + (size_t)s2 * DIM + lane4);
        ushort4 u3 = *(const ushort4*)(h + (size_t)s3 * DIM + lane4);
        a0 += n0 * bf2f(u0.x) + n1 * bf2f(u1.x) + n2 * bf2f(u2.x) + n3 * bf2f(u3.x);
        a1 += n0 * bf2f(u0.y) + n1 * bf2f(u1.y) + n2 * bf2f(u2.y) + n3 * bf2f(u3.y);
        a2 += n0 * bf2f(u0.z) + n1 * bf2f(u1.z) + n2 * bf2f(u2.z) + n3 * bf2f(u3.z);
        a3 += n0 * bf2f(u0.w) + n1 * bf2f(u1.w) + n2 * bf2f(u2.w) + n3 * bf2f(u3.w);
    }
    for (; j < r1; ++j) {
        int s = esrc[j];
        float nn = dinv[s] * dv;
        ushort4 u = *(const ushort4*)(h + (size_t)s * DIM + lane4);
        a0 += nn * bf2f(u.x);
        a1 += nn * bf2f(u.y);
        a2 += nn * bf2f(u.z);
        a3 += nn * bf2f(u.w);
    }
    ushort4 o;
    o.x = f2bf(a0); o.y = f2bf(a1); o.z = f2bf(a2); o.w = f2bf(a3);
    *(ushort4*)(agg + (size_t)d * DIM + lane4) = o;
}

// ---------------- MLP layer 2: out[n,c] = sum_k Hin[n,k]*W[c,k] + b[c]; wave per node ----------------
__global__ __launch_bounds__(256) void k_mlp2(const unsigned short* __restrict__ Hin,
        const float* __restrict__ W, const float* __restrict__ b,
        float* __restrict__ out)
{
    int gt = blockIdx.x * 256 + threadIdx.x;
    int nid = gt >> 6;
    int lane = threadIdx.x & 63;
    if (nid >= N_NODES) return;
    float h0 = bf2f(Hin[(size_t)nid * HID + lane]);
    float h1 = bf2f(Hin[(size_t)nid * HID + 64 + lane]);
    #pragma unroll
    for (int c = 0; c < NCLS; ++c) {
        float p = h0 * W[c * HID + lane] + h1 * W[c * HID + 64 + lane];
        #pragma unroll
        for (int off = 32; off > 0; off >>= 1) p += __shfl_down(p, off);
        if (lane == 0) out[nid * NCLS + c] = p + b[c];
    }
}

extern "C" void kernel_launch(void* const* d_in, const int* in_sizes, int n_in,
                              void* d_out, int out_size, void* d_ws, size_t ws_size,
                              hipStream_t stream)
{
    const float* x   = (const float*)d_in[0];
    const int*   ei  = (const int*)d_in[1];
    const float* W1  = (const float*)d_in[2];
    const float* b1  = (const float*)d_in[3];
    const float* W2  = (const float*)d_in[4];
    const float* b2  = (const float*)d_in[5];
    const float* Wm1 = (const float*)d_in[6];
    const float* bm1 = (const float*)d_in[7];
    const float* Wm2 = (const float*)d_in[8];
    const float* bm2 = (const float*)d_in[9];
    float* out = (float*)d_out;
    const int* src = ei;
    const int* dst = ei + N_EDGES;

    // workspace layout (~127 MB total):
    //   0x0000000 : dinv    fp32[N]        (400 KB)
    //   0x0080000 : rowptr  int[N+1]
    //   0x0100000 : counts  int[N]
    //   0x0180000 : cursor  int[N]
    //   0x0200000 : esrc    int[E]         (12.8 MB)
    //   0x1000000 : agg     bf16[N*DIM]    (51.2 MB)
    //   0x4800000 : hbuf    bf16[N*DIM]    (51.2 MB)
    char* ws = (char*)d_ws;
    float* dinv  = (float*)(ws + 0x0000000);
    int* rowptr  = (int*)  (ws + 0x0080000);
    int* counts  = (int*)  (ws + 0x0100000);
    int* cursor  = (int*)  (ws + 0x0180000);
    int* esrc    = (int*)  (ws + 0x0200000);
    unsigned short* agg  = (unsigned short*)(ws + 0x1000000);
    unsigned short* hbuf = (unsigned short*)(ws + 0x4800000);

    const int GB_N = (N_NODES + 255) / 256;
    const int GB_E = (N_EDGES + 255) / 256;

    // CSR build (by destination) + symmetric-norm factors
    k_zero<<<GB_N, 256, 0, stream>>>(counts, N_NODES);
    k_hist<<<GB_E, 256, 0, stream>>>(dst, counts);
    k_dinv<<<GB_N, 256, 0, stream>>>(counts, dinv);
    k_scan<<<1, 256, 0, stream>>>(counts, rowptr, cursor);
    k_bucket<<<GB_E, 256, 0, stream>>>(src, dst, cursor, esrc);

    dim3 blk(16, 16);
    dim3 grid_d((N_NODES + 63) / 64, DIM / 64);
    dim3 grid_h((N_NODES + 63) / 64, HID / 64);
    const int GATHER_B = (N_NODES + 3) / 4;   // 4 waves/block, wave per node

    // GCN layer 1: h = x@W1^T ; agg = b1 + norm-gather(h)
    k_gemm_nt<float><<<grid_d, blk, 0, stream>>>(x, W1, nullptr, hbuf, N_NODES, DIM, DIM);
    k_gather<<<GATHER_B, 256, 0, stream>>>(hbuf, rowptr, esrc, dinv, b1, agg);

    // GCN layer 2
    k_gemm_nt<unsigned short><<<grid_d, blk, 0, stream>>>(agg, W2, nullptr, hbuf, N_NODES, DIM, DIM);
    k_gather<<<GATHER_B, 256, 0, stream>>>(hbuf, rowptr, esrc, dinv, b2, agg);

    // MLP head
    k_gemm_nt<unsigned short><<<grid_h, blk, 0, stream>>>(agg, Wm1, bm1, hbuf, N_NODES, HID, DIM);
    k_mlp2<<<(N_NODES * 64) / 256, 256, 0, stream>>>(hbuf, Wm2, bm2, out);
}

// Round 6
// 1170.727 us; speedup vs baseline: 18.7737x; 1.7024x over previous
//
#include <hip/hip_runtime.h>

#define N_NODES 100000
#define N_EDGES 3200000
#define DIM 256
#define HID 128
#define NCLS 5
#define NBLK 391   // ceil(N_NODES/256)

typedef __bf16 bf16x8 __attribute__((ext_vector_type(8)));
typedef float  f32x4  __attribute__((ext_vector_type(4)));

__device__ __forceinline__ float bf2f(unsigned short u) {
    union { unsigned int i; float f; } v; v.i = ((unsigned int)u) << 16; return v.f;
}
__device__ __forceinline__ unsigned short f2bf(float f) {
    union { float f; unsigned int i; } v; v.f = f;
    unsigned int x = v.i;
    return (unsigned short)((x + 0x7FFFu + ((x >> 16) & 1u)) >> 16);
}

// ---------------- fp32 -> bf16 conversion (8 elems/thread) ----------------
__global__ void k_cvt(const float* __restrict__ in, unsigned short* __restrict__ out, int n) {
    int i8 = (blockIdx.x * 256 + threadIdx.x) * 8;
    if (i8 >= n) return;
    float4 a = *(const float4*)(in + i8);
    float4 b = *(const float4*)(in + i8 + 4);
    ushort4 lo, hi;
    lo.x = f2bf(a.x); lo.y = f2bf(a.y); lo.z = f2bf(a.z); lo.w = f2bf(a.w);
    hi.x = f2bf(b.x); hi.y = f2bf(b.y); hi.z = f2bf(b.z); hi.w = f2bf(b.w);
    *(ushort4*)(out + i8) = lo;
    *(ushort4*)(out + i8 + 4) = hi;
}

// ---------------- CSR build ----------------
__global__ void k_zero(int* p, int n) {
    int i = blockIdx.x * 256 + threadIdx.x;
    if (i < n) p[i] = 0;
}
__global__ void k_hist(const int* __restrict__ dst, int* __restrict__ counts) {
    int e = blockIdx.x * 256 + threadIdx.x;
    if (e < N_EDGES) atomicAdd(&counts[dst[e]], 1);
}
__global__ void k_dinv(const int* __restrict__ counts, float* __restrict__ dinv) {
    int i = blockIdx.x * 256 + threadIdx.x;
    if (i < N_NODES) dinv[i] = rsqrtf((float)(counts[i] + 1));   // +1 self-loop
}
// per-256-block sums of counts
__global__ __launch_bounds__(256) void k_blocksum(const int* __restrict__ counts,
        int* __restrict__ partials)
{
    __shared__ int sd[4];
    int tid = threadIdx.x;
    int i = blockIdx.x * 256 + tid;
    int v = (i < N_NODES) ? counts[i] : 0;
    #pragma unroll
    for (int off = 32; off > 0; off >>= 1) v += __shfl_down(v, off);
    if ((tid & 63) == 0) sd[tid >> 6] = v;
    __syncthreads();
    if (tid == 0) partials[blockIdx.x] = sd[0] + sd[1] + sd[2] + sd[3];
}
// exclusive scan of NBLK partials (single block, 2 chunks)
__global__ __launch_bounds__(256) void k_scanpartials(const int* __restrict__ partials,
        int* __restrict__ blockoff)
{
    __shared__ int sdata[256];
    __shared__ int s_base;
    int tid = threadIdx.x;
    if (tid == 0) s_base = 0;
    __syncthreads();
    for (int base = 0; base < NBLK; base += 256) {
        int i = base + tid;
        int v = (i < NBLK) ? partials[i] : 0;
        sdata[tid] = v;
        __syncthreads();
        #pragma unroll
        for (int off = 1; off < 256; off <<= 1) {
            int t = (tid >= off) ? sdata[tid - off] : 0;
            __syncthreads();
            sdata[tid] += t;
            __syncthreads();
        }
        if (i < NBLK) blockoff[i] = s_base + sdata[tid] - v;
        int total = sdata[255];
        __syncthreads();
        if (tid == 0) s_base += total;
        __syncthreads();
    }
}
// local exclusive scan + block offset -> rowptr/cursor
__global__ __launch_bounds__(256) void k_scanlocal(const int* __restrict__ counts,
        const int* __restrict__ blockoff, int* __restrict__ rowptr, int* __restrict__ cursor)
{
    __shared__ int sdata[256];
    int tid = threadIdx.x;
    int i = blockIdx.x * 256 + tid;
    int v = (i < N_NODES) ? counts[i] : 0;
    sdata[tid] = v;
    __syncthreads();
    #pragma unroll
    for (int off = 1; off < 256; off <<= 1) {
        int t = (tid >= off) ? sdata[tid - off] : 0;
        __syncthreads();
        sdata[tid] += t;
        __syncthreads();
    }
    if (i < N_NODES) {
        int rp = blockoff[blockIdx.x] + sdata[tid] - v;
        rowptr[i] = rp; cursor[i] = rp;
    }
    if (i == 0) rowptr[N_NODES] = N_EDGES;
}
__global__ void k_bucket(const int* __restrict__ src, const int* __restrict__ dst,
        int* __restrict__ cursor, int* __restrict__ esrc)
{
    int e = blockIdx.x * 256 + threadIdx.x;
    if (e < N_EDGES) {
        int pos = atomicAdd(&cursor[dst[e]], 1);
        esrc[pos] = src[e];
    }
}

// ---------------- MFMA bf16 GEMM: C[m,n] = (sum_k A[m,k]*B[n,k] + bias[n]) * dscale[m] ----------------
// A: MxK bf16 row-major; B: NoutxK bf16 row-major; C: bf16.
// 128x128 block tile, BK=32, 4 waves each computing a 64x64 quadrant as 4x4 MFMA 16x16x32 tiles.
__global__ __launch_bounds__(256) void k_gemm_mfma(const unsigned short* __restrict__ A,
        const unsigned short* __restrict__ B, const float* __restrict__ bias,
        const float* __restrict__ dscale, unsigned short* __restrict__ C,
        int M, int Nout, int K)
{
    __shared__ __align__(16) unsigned short As[128][32];
    __shared__ __align__(16) unsigned short Bs[128][32];
    int tid = threadIdx.x;
    int wave = tid >> 6, lane = tid & 63;
    int quad = lane >> 4, l16 = lane & 15;
    int wr = wave >> 1, wc = wave & 1;           // 64x64 quadrant
    int m0 = blockIdx.x * 128, n0 = blockIdx.y * 128;
    int srow = tid >> 1;                          // staging row: 0..127
    int scol = (tid & 1) * 16;                    // 0 or 16 (shorts); each thread covers 16 shorts = 2x uint4

    f32x4 acc[4][4] = {};
    for (int k0 = 0; k0 < K; k0 += 32) {
        int ma = m0 + srow; if (ma > M - 1) ma = M - 1;
        const unsigned short* ap = A + (size_t)ma * K + k0 + scol;
        const unsigned short* bp = B + (size_t)(n0 + srow) * K + k0 + scol;
        // uint4 = 8 shorts -> two stores to cover 16 shorts (round-5 bug: only one store -> LDS garbage)
        *(uint4*)&As[srow][scol]     = *(const uint4*)(ap);
        *(uint4*)&As[srow][scol + 8] = *(const uint4*)(ap + 8);
        *(uint4*)&Bs[srow][scol]     = *(const uint4*)(bp);
        *(uint4*)&Bs[srow][scol + 8] = *(const uint4*)(bp + 8);
        __syncthreads();
        bf16x8 af[4], bfr[4];
        #pragma unroll
        for (int r = 0; r < 4; ++r)
            af[r] = *(const bf16x8*)&As[wr * 64 + r * 16 + l16][quad * 8];
        #pragma unroll
        for (int c = 0; c < 4; ++c)
            bfr[c] = *(const bf16x8*)&Bs[wc * 64 + c * 16 + l16][quad * 8];
        #pragma unroll
        for (int r = 0; r < 4; ++r)
            #pragma unroll
            for (int c = 0; c < 4; ++c)
                acc[r][c] = __builtin_amdgcn_mfma_f32_16x16x32_bf16(af[r], bfr[c], acc[r][c], 0, 0, 0);
        __syncthreads();
    }
    // epilogue: C/D layout col=lane&15, row=quad*4+reg  [m89-verified]
    #pragma unroll
    for (int r = 0; r < 4; ++r) {
        #pragma unroll
        for (int reg = 0; reg < 4; ++reg) {
            int row = m0 + wr * 64 + r * 16 + quad * 4 + reg;
            if (row >= M) continue;
            float ds = dscale ? dscale[row] : 1.0f;
            #pragma unroll
            for (int c = 0; c < 4; ++c) {
                int col = n0 + wc * 64 + c * 16 + l16;
                float v = acc[r][c][reg];
                if (bias) v += bias[col];
                C[(size_t)row * Nout + col] = f2bf(v * ds);
            }
        }
    }
}

// ---------------- CSR gather (h pre-scaled by dinv[src]): agg[d] = bias + dv * (h'[d] + sum h'[s]) ----------------
__global__ __launch_bounds__(256) void k_gather(const unsigned short* __restrict__ h,
        const int* __restrict__ rowptr, const int* __restrict__ esrc,
        const float* __restrict__ dinv, const float* __restrict__ bias,
        unsigned short* __restrict__ agg)
{
    int d = (blockIdx.x * 256 + threadIdx.x) >> 6;
    int lane4 = (threadIdx.x & 63) * 4;
    if (d >= N_NODES) return;
    float dv = dinv[d];
    int r0 = rowptr[d], r1 = rowptr[d + 1];

    float a0, a1, a2, a3;
    {   // self-loop term: h'[d] = dinv[d]*h[d] already folded in GEMM epilogue
        ushort4 u = *(const ushort4*)(h + (size_t)d * DIM + lane4);
        a0 = bf2f(u.x); a1 = bf2f(u.y); a2 = bf2f(u.z); a3 = bf2f(u.w);
    }
    int j = r0;
    for (; j + 3 < r1; j += 4) {
        int s0 = esrc[j], s1 = esrc[j + 1], s2 = esrc[j + 2], s3 = esrc[j + 3];
        ushort4 u0 = *(const ushort4*)(h + (size_t)s0 * DIM + lane4);
        ushort4 u1 = *(const ushort4*)(h + (size_t)s1 * DIM + lane4);
        ushort4 u2 = *(const ushort4*)(h + (size_t)s2 * DIM + lane4);
        ushort4 u3 = *(const ushort4*)(h + (size_t)s3 * DIM + lane4);
        a0 += bf2f(u0.x) + bf2f(u1.x) + bf2f(u2.x) + bf2f(u3.x);
        a1 += bf2f(u0.y) + bf2f(u1.y) + bf2f(u2.y) + bf2f(u3.y);
        a2 += bf2f(u0.z) + bf2f(u1.z) + bf2f(u2.z) + bf2f(u3.z);
        a3 += bf2f(u0.w) + bf2f(u1.w) + bf2f(u2.w) + bf2f(u3.w);
    }
    for (; j < r1; ++j) {
        int s = esrc[j];
        ushort4 u = *(const ushort4*)(h + (size_t)s * DIM + lane4);
        a0 += bf2f(u.x); a1 += bf2f(u.y); a2 += bf2f(u.z); a3 += bf2f(u.w);
    }
    float4 b4 = *(const float4*)(bias + lane4);
    ushort4 o;
    o.x = f2bf(b4.x + dv * a0); o.y = f2bf(b4.y + dv * a1);
    o.z = f2bf(b4.z + dv * a2); o.w = f2bf(b4.w + dv * a3);
    *(ushort4*)(agg + (size_t)d * DIM + lane4) = o;
}

// ---------------- MLP layer 2: wave per node ----------------
__global__ __launch_bounds__(256) void k_mlp2(const unsigned short* __restrict__ Hin,
        const float* __restrict__ W, const float* __restrict__ b,
        float* __restrict__ out)
{
    int gt = blockIdx.x * 256 + threadIdx.x;
    int nid = gt >> 6;
    int lane = threadIdx.x & 63;
    if (nid >= N_NODES) return;
    float h0 = bf2f(Hin[(size_t)nid * HID + lane]);
    float h1 = bf2f(Hin[(size_t)nid * HID + 64 + lane]);
    #pragma unroll
    for (int c = 0; c < NCLS; ++c) {
        float p = h0 * W[c * HID + lane] + h1 * W[c * HID + 64 + lane];
        #pragma unroll
        for (int off = 32; off > 0; off >>= 1) p += __shfl_down(p, off);
        if (lane == 0) out[nid * NCLS + c] = p + b[c];
    }
}

extern "C" void kernel_launch(void* const* d_in, const int* in_sizes, int n_in,
                              void* d_out, int out_size, void* d_ws, size_t ws_size,
                              hipStream_t stream)
{
    const float* x   = (const float*)d_in[0];
    const int*   ei  = (const int*)d_in[1];
    const float* W1  = (const float*)d_in[2];
    const float* b1  = (const float*)d_in[3];
    const float* W2  = (const float*)d_in[4];
    const float* b2  = (const float*)d_in[5];
    const float* Wm1 = (const float*)d_in[6];
    const float* bm1 = (const float*)d_in[7];
    const float* Wm2 = (const float*)d_in[8];
    const float* bm2 = (const float*)d_in[9];
    float* out = (float*)d_out;
    const int* src = ei;
    const int* dst = ei + N_EDGES;

    // workspace layout (~127 MB; harness ws proven >= 154 MB in round 3):
    char* ws = (char*)d_ws;
    float* dinv  = (float*)(ws + 0x0000000);            // 400 KB
    int* rowptr  = (int*)  (ws + 0x0080000);            // 400 KB
    int* counts  = (int*)  (ws + 0x0100000);            // 400 KB
    int* cursor  = (int*)  (ws + 0x0180000);            // 400 KB
    int* esrc    = (int*)  (ws + 0x0200000);            // 12.8 MB
    unsigned short* w1bf  = (unsigned short*)(ws + 0x0E80000);  // 128 KB
    unsigned short* w2bf  = (unsigned short*)(ws + 0x0EA0000);  // 128 KB
    unsigned short* wm1bf = (unsigned short*)(ws + 0x0EC0000);  // 64 KB
    int* partials = (int*) (ws + 0x0ED0000);            // 2 KB
    int* blockoff = (int*) (ws + 0x0ED2000);            // 2 KB
    unsigned short* agg  = (unsigned short*)(ws + 0x1000000);   // 51.2 MB (aliases xbf)
    unsigned short* xbf  = (unsigned short*)(ws + 0x1000000);   // dead after GEMM1
    unsigned short* hbuf = (unsigned short*)(ws + 0x4800000);   // 51.2 MB

    const int GB_N = (N_NODES + 255) / 256;
    const int GB_E = (N_EDGES + 255) / 256;

    // fp32 -> bf16 conversions
    k_cvt<<<(N_NODES * DIM / 8 + 255) / 256, 256, 0, stream>>>(x, xbf, N_NODES * DIM);
    k_cvt<<<(DIM * DIM / 8 + 255) / 256, 256, 0, stream>>>(W1, w1bf, DIM * DIM);
    k_cvt<<<(DIM * DIM / 8 + 255) / 256, 256, 0, stream>>>(W2, w2bf, DIM * DIM);
    k_cvt<<<(HID * DIM / 8 + 255) / 256, 256, 0, stream>>>(Wm1, wm1bf, HID * DIM);

    // CSR build (by destination) + norm factors; hierarchical scan
    k_zero<<<GB_N, 256, 0, stream>>>(counts, N_NODES);
    k_hist<<<GB_E, 256, 0, stream>>>(dst, counts);
    k_dinv<<<GB_N, 256, 0, stream>>>(counts, dinv);
    k_blocksum<<<NBLK, 256, 0, stream>>>(counts, partials);
    k_scanpartials<<<1, 256, 0, stream>>>(partials, blockoff);
    k_scanlocal<<<NBLK, 256, 0, stream>>>(counts, blockoff, rowptr, cursor);
    k_bucket<<<GB_E, 256, 0, stream>>>(src, dst, cursor, esrc);

    dim3 grid_d((N_NODES + 127) / 128, DIM / 128);   // 782 x 2
    dim3 grid_h((N_NODES + 127) / 128, HID / 128);   // 782 x 1
    const int GATHER_B = (N_NODES + 3) / 4;

    // GCN layer 1: h' = dinv * (x@W1^T); agg = b1 + dv * gather(h')
    k_gemm_mfma<<<grid_d, 256, 0, stream>>>(xbf, w1bf, nullptr, dinv, hbuf, N_NODES, DIM, DIM);
    k_gather<<<GATHER_B, 256, 0, stream>>>(hbuf, rowptr, esrc, dinv, b1, agg);

    // GCN layer 2
    k_gemm_mfma<<<grid_d, 256, 0, stream>>>(agg, w2bf, nullptr, dinv, hbuf, N_NODES, DIM, DIM);
    k_gather<<<GATHER_B, 256, 0, stream>>>(hbuf, rowptr, esrc, dinv, b2, agg);

    // MLP head
    k_gemm_mfma<<<grid_h, 256, 0, stream>>>(agg, wm1bf, bm1, nullptr, hbuf, N_NODES, HID, DIM);
    k_mlp2<<<(N_NODES * 64) / 256, 256, 0, stream>>>(hbuf, Wm2, bm2, out);
}

// Round 7
// 918.381 us; speedup vs baseline: 23.9322x; 1.2748x over previous
//
#include <hip/hip_runtime.h>

#define N_NODES 100000
#define N_EDGES 3200000
#define DIM 256
#define HID 128
#define NCLS 5
#define NBLK 391        // ceil(N_NODES/256) for rowptr scan
#define NBUCK 782       // ceil(N_NODES/128) coarse buckets (dst>>7)
#define P1B 256         // pass-1 partition blocks
#define EPB 12500       // N_EDGES / P1B

typedef __bf16 bf16x8 __attribute__((ext_vector_type(8)));
typedef float  f32x4  __attribute__((ext_vector_type(4)));

__device__ __forceinline__ float bf2f(unsigned short u) {
    union { unsigned int i; float f; } v; v.i = ((unsigned int)u) << 16; return v.f;
}
__device__ __forceinline__ unsigned short f2bf(float f) {
    union { float f; unsigned int i; } v; v.f = f;
    unsigned int x = v.i;
    return (unsigned short)((x + 0x7FFFu + ((x >> 16) & 1u)) >> 16);
}

// ---------------- fp32 -> bf16 conversion (8 elems/thread) ----------------
__global__ void k_cvt(const float* __restrict__ in, unsigned short* __restrict__ out, int n) {
    int i8 = (blockIdx.x * 256 + threadIdx.x) * 8;
    if (i8 >= n) return;
    float4 a = *(const float4*)(in + i8);
    float4 b = *(const float4*)(in + i8 + 4);
    ushort4 lo, hi;
    lo.x = f2bf(a.x); lo.y = f2bf(a.y); lo.z = f2bf(a.z); lo.w = f2bf(a.w);
    hi.x = f2bf(b.x); hi.y = f2bf(b.y); hi.z = f2bf(b.z); hi.w = f2bf(b.w);
    *(ushort4*)(out + i8) = lo;
    *(ushort4*)(out + i8 + 4) = hi;
}

__global__ void k_zero(int* p, int n) {
    int i = blockIdx.x * 256 + threadIdx.x;
    if (i < n) p[i] = 0;
}

// ---------------- pass 1: coarse partition by dst>>7 ----------------
// per-block LDS histogram; reserve disjoint global ranges per (block,bucket)
__global__ __launch_bounds__(256) void k_p1hist(const int* __restrict__ dst,
        int* __restrict__ gcount, int* __restrict__ blockbase)
{
    __shared__ int lh[NBUCK];
    int tid = threadIdx.x;
    for (int i = tid; i < NBUCK; i += 256) lh[i] = 0;
    __syncthreads();
    int s = blockIdx.x * EPB, e1 = s + EPB;
    for (int e = s + tid; e < e1; e += 256) atomicAdd(&lh[dst[e] >> 7], 1);
    __syncthreads();
    for (int i = tid; i < NBUCK; i += 256) {
        int c = lh[i];
        blockbase[blockIdx.x * NBUCK + i] = c ? atomicAdd(&gcount[i], c) : 0;
    }
}
// exclusive scan of gcount[NBUCK] -> gbase[NBUCK+1]
__global__ __launch_bounds__(256) void k_scanb(const int* __restrict__ gcount,
        int* __restrict__ gbase)
{
    __shared__ int sdata[256];
    __shared__ int s_base;
    int tid = threadIdx.x;
    if (tid == 0) s_base = 0;
    __syncthreads();
    for (int base = 0; base < NBUCK; base += 256) {
        int i = base + tid;
        int v = (i < NBUCK) ? gcount[i] : 0;
        sdata[tid] = v;
        __syncthreads();
        #pragma unroll
        for (int off = 1; off < 256; off <<= 1) {
            int t = (tid >= off) ? sdata[tid - off] : 0;
            __syncthreads();
            sdata[tid] += t;
            __syncthreads();
        }
        if (i < NBUCK) gbase[i] = s_base + sdata[tid] - v;
        int total = sdata[255];
        __syncthreads();
        if (tid == 0) s_base += total;
        __syncthreads();
    }
    if (tid == 0) gbase[NBUCK] = N_EDGES;
}
// scatter (src,dst) pairs into bucket-partitioned ebuf (line-local writes)
__global__ __launch_bounds__(256) void k_p1scatter(const int* __restrict__ src,
        const int* __restrict__ dst, const int* __restrict__ gbase,
        const int* __restrict__ blockbase, int2* __restrict__ ebuf)
{
    __shared__ int lh[NBUCK];
    int tid = threadIdx.x;
    for (int i = tid; i < NBUCK; i += 256) lh[i] = 0;
    __syncthreads();
    int s = blockIdx.x * EPB, e1 = s + EPB;
    for (int e = s + tid; e < e1; e += 256) {
        int d = dst[e];
        int b = d >> 7;
        int r = atomicAdd(&lh[b], 1);
        int pos = gbase[b] + blockbase[blockIdx.x * NBUCK + b] + r;
        ebuf[pos] = make_int2(src[e], d);
    }
}
// ---------------- pass 2: per-bucket (128 nodes) ----------------
// per-node counts from bucketed pairs (replaces 3.2M global atomics)
__global__ __launch_bounds__(256) void k_p2hist(const int2* __restrict__ ebuf,
        const int* __restrict__ gbase, int* __restrict__ counts)
{
    __shared__ int c[128];
    int tid = threadIdx.x, b = blockIdx.x;
    if (tid < 128) c[tid] = 0;
    __syncthreads();
    int s = gbase[b], e1 = gbase[b + 1];
    for (int e = s + tid; e < e1; e += 256) atomicAdd(&c[ebuf[e].y & 127], 1);
    __syncthreads();
    if (tid < 128) {
        int node = b * 128 + tid;
        if (node < N_NODES) counts[node] = c[tid];
    }
}
// final per-dst bucket sort: LDS cursor, writes confined to ~17KB region
__global__ __launch_bounds__(256) void k_p2scatter(const int2* __restrict__ ebuf,
        const int* __restrict__ gbase, const int* __restrict__ rowptr,
        int* __restrict__ esrc)
{
    __shared__ int cur[128];
    int tid = threadIdx.x, b = blockIdx.x;
    if (tid < 128) {
        int node = b * 128 + tid;
        cur[tid] = (node < N_NODES) ? rowptr[node] : 0;
    }
    __syncthreads();
    int s = gbase[b], e1 = gbase[b + 1];
    for (int e = s + tid; e < e1; e += 256) {
        int2 p = ebuf[e];
        int pos = atomicAdd(&cur[p.y & 127], 1);
        esrc[pos] = p.x;
    }
}

// ---------------- norm + rowptr scan ----------------
__global__ void k_dinv(const int* __restrict__ counts, float* __restrict__ dinv) {
    int i = blockIdx.x * 256 + threadIdx.x;
    if (i < N_NODES) dinv[i] = rsqrtf((float)(counts[i] + 1));   // +1 self-loop
}
__global__ __launch_bounds__(256) void k_blocksum(const int* __restrict__ counts,
        int* __restrict__ partials)
{
    __shared__ int sd[4];
    int tid = threadIdx.x;
    int i = blockIdx.x * 256 + tid;
    int v = (i < N_NODES) ? counts[i] : 0;
    #pragma unroll
    for (int off = 32; off > 0; off >>= 1) v += __shfl_down(v, off);
    if ((tid & 63) == 0) sd[tid >> 6] = v;
    __syncthreads();
    if (tid == 0) partials[blockIdx.x] = sd[0] + sd[1] + sd[2] + sd[3];
}
__global__ __launch_bounds__(256) void k_scanpartials(const int* __restrict__ partials,
        int* __restrict__ blockoff)
{
    __shared__ int sdata[256];
    __shared__ int s_base;
    int tid = threadIdx.x;
    if (tid == 0) s_base = 0;
    __syncthreads();
    for (int base = 0; base < NBLK; base += 256) {
        int i = base + tid;
        int v = (i < NBLK) ? partials[i] : 0;
        sdata[tid] = v;
        __syncthreads();
        #pragma unroll
        for (int off = 1; off < 256; off <<= 1) {
            int t = (tid >= off) ? sdata[tid - off] : 0;
            __syncthreads();
            sdata[tid] += t;
            __syncthreads();
        }
        if (i < NBLK) blockoff[i] = s_base + sdata[tid] - v;
        int total = sdata[255];
        __syncthreads();
        if (tid == 0) s_base += total;
        __syncthreads();
    }
}
__global__ __launch_bounds__(256) void k_scanlocal(const int* __restrict__ counts,
        const int* __restrict__ blockoff, int* __restrict__ rowptr)
{
    __shared__ int sdata[256];
    int tid = threadIdx.x;
    int i = blockIdx.x * 256 + tid;
    int v = (i < N_NODES) ? counts[i] : 0;
    sdata[tid] = v;
    __syncthreads();
    #pragma unroll
    for (int off = 1; off < 256; off <<= 1) {
        int t = (tid >= off) ? sdata[tid - off] : 0;
        __syncthreads();
        sdata[tid] += t;
        __syncthreads();
    }
    if (i < N_NODES) rowptr[i] = blockoff[blockIdx.x] + sdata[tid] - v;
    if (i == 0) rowptr[N_NODES] = N_EDGES;
}

// ---------------- MFMA bf16 GEMM: C[m,n] = (sum_k A[m,k]*B[n,k] + bias[n]) * dscale[m] ----------------
__global__ __launch_bounds__(256) void k_gemm_mfma(const unsigned short* __restrict__ A,
        const unsigned short* __restrict__ B, const float* __restrict__ bias,
        const float* __restrict__ dscale, unsigned short* __restrict__ C,
        int M, int Nout, int K)
{
    __shared__ __align__(16) unsigned short As[128][32];
    __shared__ __align__(16) unsigned short Bs[128][32];
    int tid = threadIdx.x;
    int wave = tid >> 6, lane = tid & 63;
    int quad = lane >> 4, l16 = lane & 15;
    int wr = wave >> 1, wc = wave & 1;
    int m0 = blockIdx.x * 128, n0 = blockIdx.y * 128;
    int srow = tid >> 1;
    int scol = (tid & 1) * 16;

    f32x4 acc[4][4] = {};
    for (int k0 = 0; k0 < K; k0 += 32) {
        int ma = m0 + srow; if (ma > M - 1) ma = M - 1;
        const unsigned short* ap = A + (size_t)ma * K + k0 + scol;
        const unsigned short* bp = B + (size_t)(n0 + srow) * K + k0 + scol;
        *(uint4*)&As[srow][scol]     = *(const uint4*)(ap);
        *(uint4*)&As[srow][scol + 8] = *(const uint4*)(ap + 8);
        *(uint4*)&Bs[srow][scol]     = *(const uint4*)(bp);
        *(uint4*)&Bs[srow][scol + 8] = *(const uint4*)(bp + 8);
        __syncthreads();
        bf16x8 af[4], bfr[4];
        #pragma unroll
        for (int r = 0; r < 4; ++r)
            af[r] = *(const bf16x8*)&As[wr * 64 + r * 16 + l16][quad * 8];
        #pragma unroll
        for (int c = 0; c < 4; ++c)
            bfr[c] = *(const bf16x8*)&Bs[wc * 64 + c * 16 + l16][quad * 8];
        #pragma unroll
        for (int r = 0; r < 4; ++r)
            #pragma unroll
            for (int c = 0; c < 4; ++c)
                acc[r][c] = __builtin_amdgcn_mfma_f32_16x16x32_bf16(af[r], bfr[c], acc[r][c], 0, 0, 0);
        __syncthreads();
    }
    #pragma unroll
    for (int r = 0; r < 4; ++r) {
        #pragma unroll
        for (int reg = 0; reg < 4; ++reg) {
            int row = m0 + wr * 64 + r * 16 + quad * 4 + reg;
            if (row >= M) continue;
            float ds = dscale ? dscale[row] : 1.0f;
            #pragma unroll
            for (int c = 0; c < 4; ++c) {
                int col = n0 + wc * 64 + c * 16 + l16;
                float v = acc[r][c][reg];
                if (bias) v += bias[col];
                C[(size_t)row * Nout + col] = f2bf(v * ds);
            }
        }
    }
}

// ---------------- CSR gather: agg[d] = bias + dv * (h'[d] + sum h'[s]), 8-way unroll ----------------
__global__ __launch_bounds__(256) void k_gather(const unsigned short* __restrict__ h,
        const int* __restrict__ rowptr, const int* __restrict__ esrc,
        const float* __restrict__ dinv, const float* __restrict__ bias,
        unsigned short* __restrict__ agg)
{
    int d = (blockIdx.x * 256 + threadIdx.x) >> 6;
    int lane4 = (threadIdx.x & 63) * 4;
    if (d >= N_NODES) return;
    float dv = dinv[d];
    int r0 = rowptr[d], r1 = rowptr[d + 1];

    float a0, a1, a2, a3;
    {
        ushort4 u = *(const ushort4*)(h + (size_t)d * DIM + lane4);
        a0 = bf2f(u.x); a1 = bf2f(u.y); a2 = bf2f(u.z); a3 = bf2f(u.w);
    }
    int j = r0;
    for (; j + 7 < r1; j += 8) {
        int s0 = esrc[j],     s1 = esrc[j + 1], s2 = esrc[j + 2], s3 = esrc[j + 3];
        int s4 = esrc[j + 4], s5 = esrc[j + 5], s6 = esrc[j + 6], s7 = esrc[j + 7];
        ushort4 u0 = *(const ushort4*)(h + (size_t)s0 * DIM + lane4);
        ushort4 u1 = *(const ushort4*)(h + (size_t)s1 * DIM + lane4);
        ushort4 u2 = *(const ushort4*)(h + (size_t)s2 * DIM + lane4);
        ushort4 u3 = *(const ushort4*)(h + (size_t)s3 * DIM + lane4);
        ushort4 u4 = *(const ushort4*)(h + (size_t)s4 * DIM + lane4);
        ushort4 u5 = *(const ushort4*)(h + (size_t)s5 * DIM + lane4);
        ushort4 u6 = *(const ushort4*)(h + (size_t)s6 * DIM + lane4);
        ushort4 u7 = *(const ushort4*)(h + (size_t)s7 * DIM + lane4);
        a0 += bf2f(u0.x) + bf2f(u1.x) + bf2f(u2.x) + bf2f(u3.x)
            + bf2f(u4.x) + bf2f(u5.x) + bf2f(u6.x) + bf2f(u7.x);
        a1 += bf2f(u0.y) + bf2f(u1.y) + bf2f(u2.y) + bf2f(u3.y)
            + bf2f(u4.y) + bf2f(u5.y) + bf2f(u6.y) + bf2f(u7.y);
        a2 += bf2f(u0.z) + bf2f(u1.z) + bf2f(u2.z) + bf2f(u3.z)
            + bf2f(u4.z) + bf2f(u5.z) + bf2f(u6.z) + bf2f(u7.z);
        a3 += bf2f(u0.w) + bf2f(u1.w) + bf2f(u2.w) + bf2f(u3.w)
            + bf2f(u4.w) + bf2f(u5.w) + bf2f(u6.w) + bf2f(u7.w);
    }
    for (; j < r1; ++j) {
        int s = esrc[j];
        ushort4 u = *(const ushort4*)(h + (size_t)s * DIM + lane4);
        a0 += bf2f(u.x); a1 += bf2f(u.y); a2 += bf2f(u.z); a3 += bf2f(u.w);
    }
    float4 b4 = *(const float4*)(bias + lane4);
    ushort4 o;
    o.x = f2bf(b4.x + dv * a0); o.y = f2bf(b4.y + dv * a1);
    o.z = f2bf(b4.z + dv * a2); o.w = f2bf(b4.w + dv * a3);
    *(ushort4*)(agg + (size_t)d * DIM + lane4) = o;
}

// ---------------- MLP layer 2: wave per node ----------------
__global__ __launch_bounds__(256) void k_mlp2(const unsigned short* __restrict__ Hin,
        const float* __restrict__ W, const float* __restrict__ b,
        float* __restrict__ out)
{
    int gt = blockIdx.x * 256 + threadIdx.x;
    int nid = gt >> 6;
    int lane = threadIdx.x & 63;
    if (nid >= N_NODES) return;
    float h0 = bf2f(Hin[(size_t)nid * HID + lane]);
    float h1 = bf2f(Hin[(size_t)nid * HID + 64 + lane]);
    #pragma unroll
    for (int c = 0; c < NCLS; ++c) {
        float p = h0 * W[c * HID + lane] + h1 * W[c * HID + 64 + lane];
        #pragma unroll
        for (int off = 32; off > 0; off >>= 1) p += __shfl_down(p, off);
        if (lane == 0) out[nid * NCLS + c] = p + b[c];
    }
}

extern "C" void kernel_launch(void* const* d_in, const int* in_sizes, int n_in,
                              void* d_out, int out_size, void* d_ws, size_t ws_size,
                              hipStream_t stream)
{
    const float* x   = (const float*)d_in[0];
    const int*   ei  = (const int*)d_in[1];
    const float* W1  = (const float*)d_in[2];
    const float* b1  = (const float*)d_in[3];
    const float* W2  = (const float*)d_in[4];
    const float* b2  = (const float*)d_in[5];
    const float* Wm1 = (const float*)d_in[6];
    const float* bm1 = (const float*)d_in[7];
    const float* Wm2 = (const float*)d_in[8];
    const float* bm2 = (const float*)d_in[9];
    float* out = (float*)d_out;
    const int* src = ei;
    const int* dst = ei + N_EDGES;

    // workspace layout (~127 MB; ws >= 154 MB proven round 3):
    //   ebuf/blockbase/gcount/gbase alias hbuf's window (dead until GEMM1).
    char* ws = (char*)d_ws;
    float* dinv   = (float*)(ws + 0x0000000);            // 400 KB
    int* rowptr   = (int*)  (ws + 0x0080000);            // 400 KB
    int* counts   = (int*)  (ws + 0x0100000);            // 400 KB
    int* esrc     = (int*)  (ws + 0x0200000);            // 12.8 MB
    unsigned short* w1bf  = (unsigned short*)(ws + 0x0E80000);  // 128 KB
    unsigned short* w2bf  = (unsigned short*)(ws + 0x0EA0000);  // 128 KB
    unsigned short* wm1bf = (unsigned short*)(ws + 0x0EC0000);  // 64 KB
    int* partials = (int*) (ws + 0x0ED0000);             // 2 KB
    int* blockoff = (int*) (ws + 0x0ED2000);             // 2 KB
    unsigned short* agg  = (unsigned short*)(ws + 0x1000000);   // 51.2 MB (aliases xbf)
    unsigned short* xbf  = (unsigned short*)(ws + 0x1000000);
    unsigned short* hbuf = (unsigned short*)(ws + 0x4800000);   // 51.2 MB window:
    int2* ebuf     = (int2*)(ws + 0x4800000);            //   25.6 MB  (dead before GEMM1)
    int* blockbase = (int*) (ws + 0x6200000);            //   800 KB
    int* gcount    = (int*) (ws + 0x6300000);            //   4 KB
    int* gbase     = (int*) (ws + 0x6302000);            //   4 KB

    const int GB_N = (N_NODES + 255) / 256;

    // fp32 -> bf16 conversions
    k_cvt<<<(N_NODES * DIM / 8 + 255) / 256, 256, 0, stream>>>(x, xbf, N_NODES * DIM);
    k_cvt<<<(DIM * DIM / 8 + 255) / 256, 256, 0, stream>>>(W1, w1bf, DIM * DIM);
    k_cvt<<<(DIM * DIM / 8 + 255) / 256, 256, 0, stream>>>(W2, w2bf, DIM * DIM);
    k_cvt<<<(HID * DIM / 8 + 255) / 256, 256, 0, stream>>>(Wm1, wm1bf, HID * DIM);

    // 2-pass radix CSR build
    k_zero<<<(NBUCK + 255) / 256, 256, 0, stream>>>(gcount, NBUCK);
    k_p1hist<<<P1B, 256, 0, stream>>>(dst, gcount, blockbase);
    k_scanb<<<1, 256, 0, stream>>>(gcount, gbase);
    k_p1scatter<<<P1B, 256, 0, stream>>>(src, dst, gbase, blockbase, ebuf);
    k_p2hist<<<NBUCK, 256, 0, stream>>>(ebuf, gbase, counts);
    k_dinv<<<GB_N, 256, 0, stream>>>(counts, dinv);
    k_blocksum<<<NBLK, 256, 0, stream>>>(counts, partials);
    k_scanpartials<<<1, 256, 0, stream>>>(partials, blockoff);
    k_scanlocal<<<NBLK, 256, 0, stream>>>(counts, blockoff, rowptr);
    k_p2scatter<<<NBUCK, 256, 0, stream>>>(ebuf, gbase, rowptr, esrc);

    dim3 grid_d((N_NODES + 127) / 128, DIM / 128);
    dim3 grid_h((N_NODES + 127) / 128, HID / 128);
    const int GATHER_B = (N_NODES + 3) / 4;

    // GCN layer 1: h' = dinv * (x@W1^T); agg = b1 + dv * gather(h')
    k_gemm_mfma<<<grid_d, 256, 0, stream>>>(xbf, w1bf, nullptr, dinv, hbuf, N_NODES, DIM, DIM);
    k_gather<<<GATHER_B, 256, 0, stream>>>(hbuf, rowptr, esrc, dinv, b1, agg);

    // GCN layer 2
    k_gemm_mfma<<<grid_d, 256, 0, stream>>>(agg, w2bf, nullptr, dinv, hbuf, N_NODES, DIM, DIM);
    k_gather<<<GATHER_B, 256, 0, stream>>>(hbuf, rowptr, esrc, dinv, b2, agg);

    // MLP head
    k_gemm_mfma<<<grid_h, 256, 0, stream>>>(agg, wm1bf, bm1, nullptr, hbuf, N_NODES, HID, DIM);
    k_mlp2<<<(N_NODES * 64) / 256, 256, 0, stream>>>(hbuf, Wm2, bm2, out);
}

// Round 8
// 837.583 us; speedup vs baseline: 26.2408x; 1.0965x over previous
//
#include <hip/hip_runtime.h>

#define N_NODES 100000
#define N_EDGES 3200000
#define DIM 256
#define HID 128
#define NCLS 5
#define NBUCK 782       // ceil(N_NODES/128) coarse buckets (dst>>7)
#define P1B 256         // pass-1 partition blocks
#define EPB 12500       // N_EDGES / P1B

typedef __bf16 bf16x8 __attribute__((ext_vector_type(8)));
typedef float  f32x4  __attribute__((ext_vector_type(4)));

__device__ __forceinline__ float bf2f(unsigned short u) {
    union { unsigned int i; float f; } v; v.i = ((unsigned int)u) << 16; return v.f;
}
__device__ __forceinline__ unsigned short f2bf(float f) {
    union { float f; unsigned int i; } v; v.f = f;
    unsigned int x = v.i;
    return (unsigned short)((x + 0x7FFFu + ((x >> 16) & 1u)) >> 16);
}

// ---------------- fp32 -> bf16 conversion (weights only now) ----------------
__global__ void k_cvt(const float* __restrict__ in, unsigned short* __restrict__ out, int n) {
    int i8 = (blockIdx.x * 256 + threadIdx.x) * 8;
    if (i8 >= n) return;
    float4 a = *(const float4*)(in + i8);
    float4 b = *(const float4*)(in + i8 + 4);
    ushort4 lo, hi;
    lo.x = f2bf(a.x); lo.y = f2bf(a.y); lo.z = f2bf(a.z); lo.w = f2bf(a.w);
    hi.x = f2bf(b.x); hi.y = f2bf(b.y); hi.z = f2bf(b.z); hi.w = f2bf(b.w);
    *(ushort4*)(out + i8) = lo;
    *(ushort4*)(out + i8 + 4) = hi;
}

__global__ void k_zero(int* p, int n) {
    int i = blockIdx.x * 256 + threadIdx.x;
    if (i < n) p[i] = 0;
}

// ---------------- collapsed MLP head: Wc = Wm2 @ Wm1 [5x256], bc = Wm2@bm1 + bm2 ----------------
__global__ __launch_bounds__(256) void k_wc(const float* __restrict__ Wm1,
        const float* __restrict__ bm1, const float* __restrict__ Wm2,
        const float* __restrict__ bm2, float* __restrict__ Wc, float* __restrict__ bc)
{
    int t = threadIdx.x;   // 0..255 = output feature j
    #pragma unroll
    for (int c = 0; c < NCLS; ++c) {
        float acc = 0.0f;
        for (int k = 0; k < HID; ++k) acc += Wm2[c * HID + k] * Wm1[k * DIM + t];
        Wc[c * DIM + t] = acc;
    }
    if (t < NCLS) {
        float acc = bm2[t];
        for (int k = 0; k < HID; ++k) acc += Wm2[t * HID + k] * bm1[k];
        bc[t] = acc;
    }
}

// ---------------- pass 1: coarse partition by dst>>7 ----------------
__global__ __launch_bounds__(256) void k_p1hist(const int* __restrict__ dst,
        int* __restrict__ gcount, int* __restrict__ blockbase)
{
    __shared__ int lh[NBUCK];
    int tid = threadIdx.x;
    for (int i = tid; i < NBUCK; i += 256) lh[i] = 0;
    __syncthreads();
    int s = blockIdx.x * EPB, e1 = s + EPB;
    for (int e = s + tid; e < e1; e += 256) atomicAdd(&lh[dst[e] >> 7], 1);
    __syncthreads();
    for (int i = tid; i < NBUCK; i += 256) {
        int c = lh[i];
        blockbase[blockIdx.x * NBUCK + i] = c ? atomicAdd(&gcount[i], c) : 0;
    }
}
__global__ __launch_bounds__(256) void k_scanb(const int* __restrict__ gcount,
        int* __restrict__ gbase)
{
    __shared__ int sdata[256];
    __shared__ int s_base;
    int tid = threadIdx.x;
    if (tid == 0) s_base = 0;
    __syncthreads();
    for (int base = 0; base < NBUCK; base += 256) {
        int i = base + tid;
        int v = (i < NBUCK) ? gcount[i] : 0;
        sdata[tid] = v;
        __syncthreads();
        #pragma unroll
        for (int off = 1; off < 256; off <<= 1) {
            int t = (tid >= off) ? sdata[tid - off] : 0;
            __syncthreads();
            sdata[tid] += t;
            __syncthreads();
        }
        if (i < NBUCK) gbase[i] = s_base + sdata[tid] - v;
        int total = sdata[255];
        __syncthreads();
        if (tid == 0) s_base += total;
        __syncthreads();
    }
    if (tid == 0) gbase[NBUCK] = N_EDGES;
}
__global__ __launch_bounds__(256) void k_p1scatter(const int* __restrict__ src,
        const int* __restrict__ dst, const int* __restrict__ gbase,
        const int* __restrict__ blockbase, int2* __restrict__ ebuf)
{
    __shared__ int lh[NBUCK];
    int tid = threadIdx.x;
    for (int i = tid; i < NBUCK; i += 256) lh[i] = 0;
    __syncthreads();
    int s = blockIdx.x * EPB, e1 = s + EPB;
    for (int e = s + tid; e < e1; e += 256) {
        int d = dst[e];
        int b = d >> 7;
        int r = atomicAdd(&lh[b], 1);
        int pos = gbase[b] + blockbase[blockIdx.x * NBUCK + b] + r;
        ebuf[pos] = make_int2(src[e], d);
    }
}
// ---------------- pass 2a: per-bucket counts -> rowptr (local scan) + dinv ----------------
__global__ __launch_bounds__(256) void k_p2build(const int2* __restrict__ ebuf,
        const int* __restrict__ gbase, int* __restrict__ rowptr,
        float* __restrict__ dinv)
{
    __shared__ int c[128];
    __shared__ int sdata[128];
    int tid = threadIdx.x, b = blockIdx.x;
    if (tid < 128) c[tid] = 0;
    __syncthreads();
    int s = gbase[b], e1 = gbase[b + 1];
    for (int e = s + tid; e < e1; e += 256) atomicAdd(&c[ebuf[e].y & 127], 1);
    __syncthreads();
    int cnt = (tid < 128) ? c[tid] : 0;
    if (tid < 128) sdata[tid] = cnt;
    __syncthreads();
    #pragma unroll
    for (int off = 1; off < 128; off <<= 1) {
        int t = (tid >= off && tid < 128) ? sdata[tid - off] : 0;
        __syncthreads();
        if (tid < 128) sdata[tid] += t;
        __syncthreads();
    }
    if (tid < 128) {
        int node = b * 128 + tid;
        if (node < N_NODES) {
            rowptr[node] = gbase[b] + sdata[tid] - cnt;   // exclusive prefix
            dinv[node] = rsqrtf((float)(cnt + 1));        // +1 self-loop
        }
    }
    if (b == 0 && tid == 0) rowptr[N_NODES] = N_EDGES;
}
// ---------------- pass 2b: per-dst bucket sort (LDS cursor) ----------------
__global__ __launch_bounds__(256) void k_p2scatter(const int2* __restrict__ ebuf,
        const int* __restrict__ gbase, const int* __restrict__ rowptr,
        int* __restrict__ esrc)
{
    __shared__ int cur[128];
    int tid = threadIdx.x, b = blockIdx.x;
    if (tid < 128) {
        int node = b * 128 + tid;
        cur[tid] = (node < N_NODES) ? rowptr[node] : 0;
    }
    __syncthreads();
    int s = gbase[b], e1 = gbase[b + 1];
    for (int e = s + tid; e < e1; e += 256) {
        int2 p = ebuf[e];
        int pos = atomicAdd(&cur[p.y & 127], 1);
        esrc[pos] = p.x;
    }
}

// ---------------- MFMA bf16 GEMM: C[m,n] = (sum_k A[m,k]*B[n,k] + bias[n]) * dscale[m] ----------------
// AFP32: A is fp32 (converted to bf16 during LDS staging); else A is bf16.
template<bool AFP32>
__global__ __launch_bounds__(256) void k_gemm_mfma(const void* __restrict__ A,
        const unsigned short* __restrict__ B, const float* __restrict__ bias,
        const float* __restrict__ dscale, unsigned short* __restrict__ C,
        int M, int Nout, int K)
{
    __shared__ __align__(16) unsigned short As[128][32];
    __shared__ __align__(16) unsigned short Bs[128][32];
    int tid = threadIdx.x;
    int wave = tid >> 6, lane = tid & 63;
    int quad = lane >> 4, l16 = lane & 15;
    int wr = wave >> 1, wc = wave & 1;
    int m0 = blockIdx.x * 128, n0 = blockIdx.y * 128;
    int srow = tid >> 1;
    int scol = (tid & 1) * 16;     // each thread covers 16 shorts of a 32-short LDS row

    f32x4 acc[4][4] = {};
    for (int k0 = 0; k0 < K; k0 += 32) {
        int ma = m0 + srow; if (ma > M - 1) ma = M - 1;
        if (AFP32) {
            const float* ap = (const float*)A + (size_t)ma * K + k0 + scol;
            float4 fa = *(const float4*)(ap);
            float4 fb = *(const float4*)(ap + 4);
            float4 fc = *(const float4*)(ap + 8);
            float4 fd = *(const float4*)(ap + 12);
            ushort4 u0, u1, u2, u3;
            u0.x = f2bf(fa.x); u0.y = f2bf(fa.y); u0.z = f2bf(fa.z); u0.w = f2bf(fa.w);
            u1.x = f2bf(fb.x); u1.y = f2bf(fb.y); u1.z = f2bf(fb.z); u1.w = f2bf(fb.w);
            u2.x = f2bf(fc.x); u2.y = f2bf(fc.y); u2.z = f2bf(fc.z); u2.w = f2bf(fc.w);
            u3.x = f2bf(fd.x); u3.y = f2bf(fd.y); u3.z = f2bf(fd.z); u3.w = f2bf(fd.w);
            *(ushort4*)&As[srow][scol]      = u0;
            *(ushort4*)&As[srow][scol + 4]  = u1;
            *(ushort4*)&As[srow][scol + 8]  = u2;
            *(ushort4*)&As[srow][scol + 12] = u3;
        } else {
            const unsigned short* ap = (const unsigned short*)A + (size_t)ma * K + k0 + scol;
            *(uint4*)&As[srow][scol]     = *(const uint4*)(ap);
            *(uint4*)&As[srow][scol + 8] = *(const uint4*)(ap + 8);
        }
        const unsigned short* bp = B + (size_t)(n0 + srow) * K + k0 + scol;
        *(uint4*)&Bs[srow][scol]     = *(const uint4*)(bp);
        *(uint4*)&Bs[srow][scol + 8] = *(const uint4*)(bp + 8);
        __syncthreads();
        bf16x8 af[4], bfr[4];
        #pragma unroll
        for (int r = 0; r < 4; ++r)
            af[r] = *(const bf16x8*)&As[wr * 64 + r * 16 + l16][quad * 8];
        #pragma unroll
        for (int c = 0; c < 4; ++c)
            bfr[c] = *(const bf16x8*)&Bs[wc * 64 + c * 16 + l16][quad * 8];
        #pragma unroll
        for (int r = 0; r < 4; ++r)
            #pragma unroll
            for (int c = 0; c < 4; ++c)
                acc[r][c] = __builtin_amdgcn_mfma_f32_16x16x32_bf16(af[r], bfr[c], acc[r][c], 0, 0, 0);
        __syncthreads();
    }
    #pragma unroll
    for (int r = 0; r < 4; ++r) {
        #pragma unroll
        for (int reg = 0; reg < 4; ++reg) {
            int row = m0 + wr * 64 + r * 16 + quad * 4 + reg;
            if (row >= M) continue;
            float ds = dscale ? dscale[row] : 1.0f;
            #pragma unroll
            for (int c = 0; c < 4; ++c) {
                int col = n0 + wc * 64 + c * 16 + l16;
                float v = acc[r][c][reg];
                if (bias) v += bias[col];
                C[(size_t)row * Nout + col] = f2bf(v * ds);
            }
        }
    }
}

// ---------------- gather accumulate core (wave per node, 8-way unroll) ----------------
__device__ __forceinline__ void gather_row(const unsigned short* __restrict__ h,
        int d, int lane4, int r0, int r1, const int* __restrict__ esrc,
        float& a0, float& a1, float& a2, float& a3)
{
    {   // self-loop term: h'[d] = dinv[d]*h[d] folded in GEMM epilogue
        ushort4 u = *(const ushort4*)(h + (size_t)d * DIM + lane4);
        a0 = bf2f(u.x); a1 = bf2f(u.y); a2 = bf2f(u.z); a3 = bf2f(u.w);
    }
    int j = r0;
    for (; j + 7 < r1; j += 8) {
        int s0 = esrc[j],     s1 = esrc[j + 1], s2 = esrc[j + 2], s3 = esrc[j + 3];
        int s4 = esrc[j + 4], s5 = esrc[j + 5], s6 = esrc[j + 6], s7 = esrc[j + 7];
        ushort4 u0 = *(const ushort4*)(h + (size_t)s0 * DIM + lane4);
        ushort4 u1 = *(const ushort4*)(h + (size_t)s1 * DIM + lane4);
        ushort4 u2 = *(const ushort4*)(h + (size_t)s2 * DIM + lane4);
        ushort4 u3 = *(const ushort4*)(h + (size_t)s3 * DIM + lane4);
        ushort4 u4 = *(const ushort4*)(h + (size_t)s4 * DIM + lane4);
        ushort4 u5 = *(const ushort4*)(h + (size_t)s5 * DIM + lane4);
        ushort4 u6 = *(const ushort4*)(h + (size_t)s6 * DIM + lane4);
        ushort4 u7 = *(const ushort4*)(h + (size_t)s7 * DIM + lane4);
        a0 += bf2f(u0.x) + bf2f(u1.x) + bf2f(u2.x) + bf2f(u3.x)
            + bf2f(u4.x) + bf2f(u5.x) + bf2f(u6.x) + bf2f(u7.x);
        a1 += bf2f(u0.y) + bf2f(u1.y) + bf2f(u2.y) + bf2f(u3.y)
            + bf2f(u4.y) + bf2f(u5.y) + bf2f(u6.y) + bf2f(u7.y);
        a2 += bf2f(u0.z) + bf2f(u1.z) + bf2f(u2.z) + bf2f(u3.z)
            + bf2f(u4.z) + bf2f(u5.z) + bf2f(u6.z) + bf2f(u7.z);
        a3 += bf2f(u0.w) + bf2f(u1.w) + bf2f(u2.w) + bf2f(u3.w)
            + bf2f(u4.w) + bf2f(u5.w) + bf2f(u6.w) + bf2f(u7.w);
    }
    for (; j < r1; ++j) {
        int s = esrc[j];
        ushort4 u = *(const ushort4*)(h + (size_t)s * DIM + lane4);
        a0 += bf2f(u.x); a1 += bf2f(u.y); a2 += bf2f(u.z); a3 += bf2f(u.w);
    }
}

// gather -> bf16 agg (layer 1)
__global__ __launch_bounds__(256) void k_gather(const unsigned short* __restrict__ h,
        const int* __restrict__ rowptr, const int* __restrict__ esrc,
        const float* __restrict__ dinv, const float* __restrict__ bias,
        unsigned short* __restrict__ agg)
{
    int d = (blockIdx.x * 256 + threadIdx.x) >> 6;
    int lane4 = (threadIdx.x & 63) * 4;
    if (d >= N_NODES) return;
    float dv = dinv[d];
    float a0, a1, a2, a3;
    gather_row(h, d, lane4, rowptr[d], rowptr[d + 1], esrc, a0, a1, a2, a3);
    float4 b4 = *(const float4*)(bias + lane4);
    ushort4 o;
    o.x = f2bf(b4.x + dv * a0); o.y = f2bf(b4.y + dv * a1);
    o.z = f2bf(b4.z + dv * a2); o.w = f2bf(b4.w + dv * a3);
    *(ushort4*)(agg + (size_t)d * DIM + lane4) = o;
}

// gather + fused collapsed-MLP head (layer 2): out[d,c] = (b2 + dv*gath) . Wc[c,:] + bc[c]
__global__ __launch_bounds__(256) void k_gather_head(const unsigned short* __restrict__ h,
        const int* __restrict__ rowptr, const int* __restrict__ esrc,
        const float* __restrict__ dinv, const float* __restrict__ bias,
        const float* __restrict__ Wc, const float* __restrict__ bc,
        float* __restrict__ out)
{
    int d = (blockIdx.x * 256 + threadIdx.x) >> 6;
    int lane = threadIdx.x & 63;
    int lane4 = lane * 4;
    if (d >= N_NODES) return;
    float dv = dinv[d];
    float a0, a1, a2, a3;
    gather_row(h, d, lane4, rowptr[d], rowptr[d + 1], esrc, a0, a1, a2, a3);
    float4 b4 = *(const float4*)(bias + lane4);
    float r0 = b4.x + dv * a0, r1 = b4.y + dv * a1;
    float r2 = b4.z + dv * a2, r3 = b4.w + dv * a3;
    float p[NCLS];
    #pragma unroll
    for (int c = 0; c < NCLS; ++c) {
        float4 w = *(const float4*)(Wc + c * DIM + lane4);
        float s = r0 * w.x + r1 * w.y + r2 * w.z + r3 * w.w;
        #pragma unroll
        for (int off = 32; off > 0; off >>= 1) s += __shfl_xor(s, off);
        p[c] = s;
    }
    if (lane == 0) {
        #pragma unroll
        for (int c = 0; c < NCLS; ++c) out[(size_t)d * NCLS + c] = p[c] + bc[c];
    }
}

extern "C" void kernel_launch(void* const* d_in, const int* in_sizes, int n_in,
                              void* d_out, int out_size, void* d_ws, size_t ws_size,
                              hipStream_t stream)
{
    const float* x   = (const float*)d_in[0];
    const int*   ei  = (const int*)d_in[1];
    const float* W1  = (const float*)d_in[2];
    const float* b1  = (const float*)d_in[3];
    const float* W2  = (const float*)d_in[4];
    const float* b2  = (const float*)d_in[5];
    const float* Wm1 = (const float*)d_in[6];
    const float* bm1 = (const float*)d_in[7];
    const float* Wm2 = (const float*)d_in[8];
    const float* bm2 = (const float*)d_in[9];
    float* out = (float*)d_out;
    const int* src = ei;
    const int* dst = ei + N_EDGES;

    // workspace (~127 MB; ws >= 154 MB proven round 3). ebuf/blockbase/gcount/gbase
    // alias hbuf's window (build phase finishes before GEMM1 writes hbuf).
    char* ws = (char*)d_ws;
    float* dinv   = (float*)(ws + 0x0000000);            // 400 KB
    int* rowptr   = (int*)  (ws + 0x0080000);            // 400 KB
    int* esrc     = (int*)  (ws + 0x0200000);            // 12.8 MB
    unsigned short* w1bf = (unsigned short*)(ws + 0x0E80000);   // 128 KB
    unsigned short* w2bf = (unsigned short*)(ws + 0x0EA0000);   // 128 KB
    float* Wc     = (float*)(ws + 0x0EC0000);            // 5 KB
    float* bc     = (float*)(ws + 0x0EC2000);            // 20 B
    unsigned short* agg  = (unsigned short*)(ws + 0x1000000);   // 51.2 MB
    unsigned short* hbuf = (unsigned short*)(ws + 0x4800000);   // 51.2 MB window:
    int2* ebuf     = (int2*)(ws + 0x4800000);            //   25.6 MB
    int* blockbase = (int*) (ws + 0x6200000);            //   800 KB
    int* gcount    = (int*) (ws + 0x6300000);            //   4 KB
    int* gbase     = (int*) (ws + 0x6302000);            //   4 KB

    // weight prep (bf16 copies + collapsed head)
    k_cvt<<<(DIM * DIM / 8 + 255) / 256, 256, 0, stream>>>(W1, w1bf, DIM * DIM);
    k_cvt<<<(DIM * DIM / 8 + 255) / 256, 256, 0, stream>>>(W2, w2bf, DIM * DIM);
    k_wc<<<1, 256, 0, stream>>>(Wm1, bm1, Wm2, bm2, Wc, bc);

    // 2-pass radix CSR build (+ rowptr/dinv folded into pass 2a)
    k_zero<<<(NBUCK + 255) / 256, 256, 0, stream>>>(gcount, NBUCK);
    k_p1hist<<<P1B, 256, 0, stream>>>(dst, gcount, blockbase);
    k_scanb<<<1, 256, 0, stream>>>(gcount, gbase);
    k_p1scatter<<<P1B, 256, 0, stream>>>(src, dst, gbase, blockbase, ebuf);
    k_p2build<<<NBUCK, 256, 0, stream>>>(ebuf, gbase, rowptr, dinv);
    k_p2scatter<<<NBUCK, 256, 0, stream>>>(ebuf, gbase, rowptr, esrc);

    dim3 grid_d((N_NODES + 127) / 128, DIM / 128);
    const int GATHER_B = (N_NODES + 3) / 4;

    // GCN layer 1: h' = dinv * (x@W1^T)  (fp32 x converted in staging); agg = b1 + dv*gather(h')
    k_gemm_mfma<true><<<grid_d, 256, 0, stream>>>(x, w1bf, nullptr, dinv, hbuf, N_NODES, DIM, DIM);
    k_gather<<<GATHER_B, 256, 0, stream>>>(hbuf, rowptr, esrc, dinv, b1, agg);

    // GCN layer 2: h' = dinv * (agg@W2^T); out = head(b2 + dv*gather(h'))
    k_gemm_mfma<false><<<grid_d, 256, 0, stream>>>(agg, w2bf, nullptr, dinv, hbuf, N_NODES, DIM, DIM);
    k_gather_head<<<GATHER_B, 256, 0, stream>>>(hbuf, rowptr, esrc, dinv, b2, Wc, bc, out);
}

// Round 9
// 633.205 us; speedup vs baseline: 34.7105x; 1.3228x over previous
//
#include <hip/hip_runtime.h>

#define N_NODES 100000
#define N_EDGES 3200000
#define DIM 256
#define HID 128
#define NCLS 5
#define NBUCK 782       // ceil(N_NODES/128) coarse buckets (dst>>7)
#define P1B 256         // pass-1 partition blocks
#define EPB 12500       // N_EDGES / P1B

typedef __bf16 bf16x8 __attribute__((ext_vector_type(8)));
typedef float  f32x4  __attribute__((ext_vector_type(4)));

__device__ __forceinline__ float bf2f(unsigned short u) {
    union { unsigned int i; float f; } v; v.i = ((unsigned int)u) << 16; return v.f;
}
__device__ __forceinline__ unsigned short f2bf(float f) {
    union { float f; unsigned int i; } v; v.f = f;
    unsigned int x = v.i;
    return (unsigned short)((x + 0x7FFFu + ((x >> 16) & 1u)) >> 16);
}

// ---------------- fp32 -> bf16 conversion (W1 only) ----------------
__global__ void k_cvt(const float* __restrict__ in, unsigned short* __restrict__ out, int n) {
    int i8 = (blockIdx.x * 256 + threadIdx.x) * 8;
    if (i8 >= n) return;
    float4 a = *(const float4*)(in + i8);
    float4 b = *(const float4*)(in + i8 + 4);
    ushort4 lo, hi;
    lo.x = f2bf(a.x); lo.y = f2bf(a.y); lo.z = f2bf(a.z); lo.w = f2bf(a.w);
    hi.x = f2bf(b.x); hi.y = f2bf(b.y); hi.z = f2bf(b.z); hi.w = f2bf(b.w);
    *(ushort4*)(out + i8) = lo;
    *(ushort4*)(out + i8 + 4) = hi;
}

__global__ void k_zero(int* p, int n) {
    int i = blockIdx.x * 256 + threadIdx.x;
    if (i < n) p[i] = 0;
}

// ---------------- head precompute (single block) ----------------
// Wc = Wm2@Wm1 [5x256]; W2c[c,i] = sum_o Wc[c,o]*W2[o,i]  (5x256);
// bc2[c] = sum_o Wc[c,o]*b2[o] + sum_k Wm2[c,k]*bm1[k] + bm2[c]
__global__ __launch_bounds__(256) void k_head_prep(const float* __restrict__ W2,
        const float* __restrict__ b2, const float* __restrict__ Wm1,
        const float* __restrict__ bm1, const float* __restrict__ Wm2,
        const float* __restrict__ bm2, float* __restrict__ W2c, float* __restrict__ bc2)
{
    __shared__ float WcL[NCLS][DIM];
    int t = threadIdx.x;   // 0..255
    #pragma unroll
    for (int c = 0; c < NCLS; ++c) {
        float acc = 0.0f;
        for (int k = 0; k < HID; ++k) acc += Wm2[c * HID + k] * Wm1[k * DIM + t];
        WcL[c][t] = acc;
    }
    __syncthreads();
    float acc[NCLS] = {0, 0, 0, 0, 0};
    for (int o = 0; o < DIM; ++o) {
        float w = W2[o * DIM + t];
        #pragma unroll
        for (int c = 0; c < NCLS; ++c) acc[c] += WcL[c][o] * w;
    }
    #pragma unroll
    for (int c = 0; c < NCLS; ++c) W2c[c * DIM + t] = acc[c];
    if (t < NCLS) {
        float b = bm2[t];
        for (int k = 0; k < HID; ++k) b += Wm2[t * HID + k] * bm1[k];
        for (int o = 0; o < DIM; ++o) b += WcL[t][o] * b2[o];
        bc2[t] = b;
    }
}

// ---------------- pass 1: coarse partition by dst>>7 ----------------
__global__ __launch_bounds__(256) void k_p1hist(const int* __restrict__ dst,
        int* __restrict__ gcount, int* __restrict__ blockbase)
{
    __shared__ int lh[NBUCK];
    int tid = threadIdx.x;
    for (int i = tid; i < NBUCK; i += 256) lh[i] = 0;
    __syncthreads();
    int s = blockIdx.x * EPB, e1 = s + EPB;
    for (int e = s + tid; e < e1; e += 256) atomicAdd(&lh[dst[e] >> 7], 1);
    __syncthreads();
    for (int i = tid; i < NBUCK; i += 256) {
        int c = lh[i];
        blockbase[blockIdx.x * NBUCK + i] = c ? atomicAdd(&gcount[i], c) : 0;
    }
}
__global__ __launch_bounds__(256) void k_scanb(const int* __restrict__ gcount,
        int* __restrict__ gbase)
{
    __shared__ int sdata[256];
    __shared__ int s_base;
    int tid = threadIdx.x;
    if (tid == 0) s_base = 0;
    __syncthreads();
    for (int base = 0; base < NBUCK; base += 256) {
        int i = base + tid;
        int v = (i < NBUCK) ? gcount[i] : 0;
        sdata[tid] = v;
        __syncthreads();
        #pragma unroll
        for (int off = 1; off < 256; off <<= 1) {
            int t = (tid >= off) ? sdata[tid - off] : 0;
            __syncthreads();
            sdata[tid] += t;
            __syncthreads();
        }
        if (i < NBUCK) gbase[i] = s_base + sdata[tid] - v;
        int total = sdata[255];
        __syncthreads();
        if (tid == 0) s_base += total;
        __syncthreads();
    }
    if (tid == 0) gbase[NBUCK] = N_EDGES;
}
__global__ __launch_bounds__(256) void k_p1scatter(const int* __restrict__ src,
        const int* __restrict__ dst, const int* __restrict__ gbase,
        const int* __restrict__ blockbase, int2* __restrict__ ebuf)
{
    __shared__ int lh[NBUCK];
    int tid = threadIdx.x;
    for (int i = tid; i < NBUCK; i += 256) lh[i] = 0;
    __syncthreads();
    int s = blockIdx.x * EPB, e1 = s + EPB;
    for (int e = s + tid; e < e1; e += 256) {
        int d = dst[e];
        int b = d >> 7;
        int r = atomicAdd(&lh[b], 1);
        int pos = gbase[b] + blockbase[blockIdx.x * NBUCK + b] + r;
        ebuf[pos] = make_int2(src[e], d);
    }
}
// ---------------- pass 2 (merged): counts -> rowptr/dinv, then bucket sort ----------------
__global__ __launch_bounds__(256) void k_p2(const int2* __restrict__ ebuf,
        const int* __restrict__ gbase, int* __restrict__ rowptr,
        float* __restrict__ dinv, int* __restrict__ esrc)
{
    __shared__ int c[128];
    __shared__ int sdata[128];
    __shared__ int cur[128];
    int tid = threadIdx.x, b = blockIdx.x;
    if (tid < 128) c[tid] = 0;
    __syncthreads();
    int s = gbase[b], e1 = gbase[b + 1];
    for (int e = s + tid; e < e1; e += 256) atomicAdd(&c[ebuf[e].y & 127], 1);
    __syncthreads();
    int cnt = (tid < 128) ? c[tid] : 0;
    if (tid < 128) sdata[tid] = cnt;
    __syncthreads();
    #pragma unroll
    for (int off = 1; off < 128; off <<= 1) {
        int t = (tid >= off && tid < 128) ? sdata[tid - off] : 0;
        __syncthreads();
        if (tid < 128) sdata[tid] += t;
        __syncthreads();
    }
    if (tid < 128) {
        int rp = gbase[b] + sdata[tid] - cnt;   // exclusive prefix
        cur[tid] = rp;
        int node = b * 128 + tid;
        if (node < N_NODES) {
            rowptr[node] = rp;
            dinv[node] = rsqrtf((float)(cnt + 1));   // +1 self-loop
        }
    }
    if (b == 0 && tid == 0) rowptr[N_NODES] = N_EDGES;
    __syncthreads();
    for (int e = s + tid; e < e1; e += 256) {
        int2 p = ebuf[e];
        int pos = atomicAdd(&cur[p.y & 127], 1);
        esrc[pos] = p.x;
    }
}

// ---------------- MFMA bf16 GEMM: C[m,n] = (sum_k A[m,k]*B[n,k]) * dscale[m] ----------------
template<bool AFP32>
__global__ __launch_bounds__(256) void k_gemm_mfma(const void* __restrict__ A,
        const unsigned short* __restrict__ B, const float* __restrict__ bias,
        const float* __restrict__ dscale, unsigned short* __restrict__ C,
        int M, int Nout, int K)
{
    __shared__ __align__(16) unsigned short As[128][32];
    __shared__ __align__(16) unsigned short Bs[128][32];
    int tid = threadIdx.x;
    int wave = tid >> 6, lane = tid & 63;
    int quad = lane >> 4, l16 = lane & 15;
    int wr = wave >> 1, wc = wave & 1;
    int m0 = blockIdx.x * 128, n0 = blockIdx.y * 128;
    int srow = tid >> 1;
    int scol = (tid & 1) * 16;

    f32x4 acc[4][4] = {};
    for (int k0 = 0; k0 < K; k0 += 32) {
        int ma = m0 + srow; if (ma > M - 1) ma = M - 1;
        if (AFP32) {
            const float* ap = (const float*)A + (size_t)ma * K + k0 + scol;
            float4 fa = *(const float4*)(ap);
            float4 fb = *(const float4*)(ap + 4);
            float4 fc = *(const float4*)(ap + 8);
            float4 fd = *(const float4*)(ap + 12);
            ushort4 u0, u1, u2, u3;
            u0.x = f2bf(fa.x); u0.y = f2bf(fa.y); u0.z = f2bf(fa.z); u0.w = f2bf(fa.w);
            u1.x = f2bf(fb.x); u1.y = f2bf(fb.y); u1.z = f2bf(fb.z); u1.w = f2bf(fb.w);
            u2.x = f2bf(fc.x); u2.y = f2bf(fc.y); u2.z = f2bf(fc.z); u2.w = f2bf(fc.w);
            u3.x = f2bf(fd.x); u3.y = f2bf(fd.y); u3.z = f2bf(fd.z); u3.w = f2bf(fd.w);
            *(ushort4*)&As[srow][scol]      = u0;
            *(ushort4*)&As[srow][scol + 4]  = u1;
            *(ushort4*)&As[srow][scol + 8]  = u2;
            *(ushort4*)&As[srow][scol + 12] = u3;
        } else {
            const unsigned short* ap = (const unsigned short*)A + (size_t)ma * K + k0 + scol;
            *(uint4*)&As[srow][scol]     = *(const uint4*)(ap);
            *(uint4*)&As[srow][scol + 8] = *(const uint4*)(ap + 8);
        }
        const unsigned short* bp = B + (size_t)(n0 + srow) * K + k0 + scol;
        *(uint4*)&Bs[srow][scol]     = *(const uint4*)(bp);
        *(uint4*)&Bs[srow][scol + 8] = *(const uint4*)(bp + 8);
        __syncthreads();
        bf16x8 af[4], bfr[4];
        #pragma unroll
        for (int r = 0; r < 4; ++r)
            af[r] = *(const bf16x8*)&As[wr * 64 + r * 16 + l16][quad * 8];
        #pragma unroll
        for (int c = 0; c < 4; ++c)
            bfr[c] = *(const bf16x8*)&Bs[wc * 64 + c * 16 + l16][quad * 8];
        #pragma unroll
        for (int r = 0; r < 4; ++r)
            #pragma unroll
            for (int c = 0; c < 4; ++c)
                acc[r][c] = __builtin_amdgcn_mfma_f32_16x16x32_bf16(af[r], bfr[c], acc[r][c], 0, 0, 0);
        __syncthreads();
    }
    #pragma unroll
    for (int r = 0; r < 4; ++r) {
        #pragma unroll
        for (int reg = 0; reg < 4; ++reg) {
            int row = m0 + wr * 64 + r * 16 + quad * 4 + reg;
            if (row >= M) continue;
            float ds = dscale ? dscale[row] : 1.0f;
            #pragma unroll
            for (int c = 0; c < 4; ++c) {
                int col = n0 + wc * 64 + c * 16 + l16;
                float v = acc[r][c][reg];
                if (bias) v += bias[col];
                C[(size_t)row * Nout + col] = f2bf(v * ds);
            }
        }
    }
}

// ---------------- gather accumulate core (wave per node, 8-way unroll) ----------------
__device__ __forceinline__ void gather_row(const unsigned short* __restrict__ h,
        int d, int lane4, int r0, int r1, const int* __restrict__ esrc,
        float& a0, float& a1, float& a2, float& a3)
{
    {   // self-loop term: h'[d] = dinv[d]*h[d] folded in GEMM epilogue
        ushort4 u = *(const ushort4*)(h + (size_t)d * DIM + lane4);
        a0 = bf2f(u.x); a1 = bf2f(u.y); a2 = bf2f(u.z); a3 = bf2f(u.w);
    }
    int j = r0;
    for (; j + 7 < r1; j += 8) {
        int s0 = esrc[j],     s1 = esrc[j + 1], s2 = esrc[j + 2], s3 = esrc[j + 3];
        int s4 = esrc[j + 4], s5 = esrc[j + 5], s6 = esrc[j + 6], s7 = esrc[j + 7];
        ushort4 u0 = *(const ushort4*)(h + (size_t)s0 * DIM + lane4);
        ushort4 u1 = *(const ushort4*)(h + (size_t)s1 * DIM + lane4);
        ushort4 u2 = *(const ushort4*)(h + (size_t)s2 * DIM + lane4);
        ushort4 u3 = *(const ushort4*)(h + (size_t)s3 * DIM + lane4);
        ushort4 u4 = *(const ushort4*)(h + (size_t)s4 * DIM + lane4);
        ushort4 u5 = *(const ushort4*)(h + (size_t)s5 * DIM + lane4);
        ushort4 u6 = *(const ushort4*)(h + (size_t)s6 * DIM + lane4);
        ushort4 u7 = *(const ushort4*)(h + (size_t)s7 * DIM + lane4);
        a0 += bf2f(u0.x) + bf2f(u1.x) + bf2f(u2.x) + bf2f(u3.x)
            + bf2f(u4.x) + bf2f(u5.x) + bf2f(u6.x) + bf2f(u7.x);
        a1 += bf2f(u0.y) + bf2f(u1.y) + bf2f(u2.y) + bf2f(u3.y)
            + bf2f(u4.y) + bf2f(u5.y) + bf2f(u6.y) + bf2f(u7.y);
        a2 += bf2f(u0.z) + bf2f(u1.z) + bf2f(u2.z) + bf2f(u3.z)
            + bf2f(u4.z) + bf2f(u5.z) + bf2f(u6.z) + bf2f(u7.z);
        a3 += bf2f(u0.w) + bf2f(u1.w) + bf2f(u2.w) + bf2f(u3.w)
            + bf2f(u4.w) + bf2f(u5.w) + bf2f(u6.w) + bf2f(u7.w);
    }
    for (; j < r1; ++j) {
        int s = esrc[j];
        ushort4 u = *(const ushort4*)(h + (size_t)s * DIM + lane4);
        a0 += bf2f(u.x); a1 += bf2f(u.y); a2 += bf2f(u.z); a3 += bf2f(u.w);
    }
}

// gather layer-1 + fused 5-wide layer-2 transform:
// r = b1 + dv*gather(h');  t'[d][c] = dv * (r . W2c[c,:])
__global__ __launch_bounds__(256) void k_gather_t(const unsigned short* __restrict__ h,
        const int* __restrict__ rowptr, const int* __restrict__ esrc,
        const float* __restrict__ dinv, const float* __restrict__ b1,
        const float* __restrict__ W2c, float* __restrict__ tbuf)
{
    int d = (blockIdx.x * 256 + threadIdx.x) >> 6;
    int lane = threadIdx.x & 63;
    int lane4 = lane * 4;
    if (d >= N_NODES) return;
    float dv = dinv[d];
    float a0, a1, a2, a3;
    gather_row(h, d, lane4, rowptr[d], rowptr[d + 1], esrc, a0, a1, a2, a3);
    float4 b4 = *(const float4*)(b1 + lane4);
    float r0 = b4.x + dv * a0, r1 = b4.y + dv * a1;
    float r2 = b4.z + dv * a2, r3 = b4.w + dv * a3;
    float p[NCLS];
    #pragma unroll
    for (int c = 0; c < NCLS; ++c) {
        float4 w = *(const float4*)(W2c + c * DIM + lane4);
        float s = r0 * w.x + r1 * w.y + r2 * w.z + r3 * w.w;
        #pragma unroll
        for (int off = 32; off > 0; off >>= 1) s += __shfl_xor(s, off);
        p[c] = s;
    }
    if (lane == 0) {
        #pragma unroll
        for (int c = 0; c < NCLS; ++c) tbuf[(size_t)d * 8 + c] = dv * p[c];
    }
}

// layer-2 aggregation over 5-wide fp32 rows (L2-resident): 4 lanes per node
__global__ __launch_bounds__(256) void k_gather_out(const float* __restrict__ tbuf,
        const int* __restrict__ rowptr, const int* __restrict__ esrc,
        const float* __restrict__ dinv, const float* __restrict__ bc2,
        float* __restrict__ out)
{
    int gid = blockIdx.x * 256 + threadIdx.x;
    int d = gid >> 2, sub = gid & 3;
    if (d >= N_NODES) return;
    float acc0 = 0, acc1 = 0, acc2 = 0, acc3 = 0, acc4 = 0;
    int r0 = rowptr[d], r1 = rowptr[d + 1];
    for (int j = r0 + sub; j < r1; j += 4) {
        int s = esrc[j];
        float4 v = *(const float4*)(tbuf + (size_t)s * 8);
        float v4 = tbuf[(size_t)s * 8 + 4];
        acc0 += v.x; acc1 += v.y; acc2 += v.z; acc3 += v.w; acc4 += v4;
    }
    if (sub == 0) {   // self-loop
        float4 v = *(const float4*)(tbuf + (size_t)d * 8);
        float v4 = tbuf[(size_t)d * 8 + 4];
        acc0 += v.x; acc1 += v.y; acc2 += v.z; acc3 += v.w; acc4 += v4;
    }
    #pragma unroll
    for (int off = 1; off < 4; off <<= 1) {
        acc0 += __shfl_xor(acc0, off);
        acc1 += __shfl_xor(acc1, off);
        acc2 += __shfl_xor(acc2, off);
        acc3 += __shfl_xor(acc3, off);
        acc4 += __shfl_xor(acc4, off);
    }
    if (sub == 0) {
        float dv = dinv[d];
        out[(size_t)d * NCLS + 0] = dv * acc0 + bc2[0];
        out[(size_t)d * NCLS + 1] = dv * acc1 + bc2[1];
        out[(size_t)d * NCLS + 2] = dv * acc2 + bc2[2];
        out[(size_t)d * NCLS + 3] = dv * acc3 + bc2[3];
        out[(size_t)d * NCLS + 4] = dv * acc4 + bc2[4];
    }
}

extern "C" void kernel_launch(void* const* d_in, const int* in_sizes, int n_in,
                              void* d_out, int out_size, void* d_ws, size_t ws_size,
                              hipStream_t stream)
{
    const float* x   = (const float*)d_in[0];
    const int*   ei  = (const int*)d_in[1];
    const float* W1  = (const float*)d_in[2];
    const float* b1  = (const float*)d_in[3];
    const float* W2  = (const float*)d_in[4];
    const float* b2  = (const float*)d_in[5];
    const float* Wm1 = (const float*)d_in[6];
    const float* bm1 = (const float*)d_in[7];
    const float* Wm2 = (const float*)d_in[8];
    const float* bm2 = (const float*)d_in[9];
    float* out = (float*)d_out;
    const int* src = ei;
    const int* dst = ei + N_EDGES;

    // workspace (~126 MB; ws >= 154 MB proven). ebuf window aliases hbuf
    // (build phase stream-orders before GEMM1 writes hbuf).
    char* ws = (char*)d_ws;
    float* dinv   = (float*)(ws + 0x0000000);            // 400 KB
    int* rowptr   = (int*)  (ws + 0x0080000);            // 400 KB
    int* esrc     = (int*)  (ws + 0x0200000);            // 12.8 MB
    unsigned short* w1bf = (unsigned short*)(ws + 0x0E80000);   // 128 KB
    float* W2c    = (float*)(ws + 0x0EA0000);            // 5 KB
    float* bc2    = (float*)(ws + 0x0EA2000);            // 20 B
    float* tbuf   = (float*)(ws + 0x0EB0000);            // 3.2 MB (stride 8 fp32/node)
    unsigned short* hbuf = (unsigned short*)(ws + 0x4800000);   // 51.2 MB window:
    int2* ebuf     = (int2*)(ws + 0x4800000);            //   25.6 MB
    int* blockbase = (int*) (ws + 0x6200000);            //   800 KB
    int* gcount    = (int*) (ws + 0x6300000);            //   4 KB
    int* gbase     = (int*) (ws + 0x6302000);            //   4 KB

    // prep: W1 bf16 copy + collapsed head (W2c = (Wm2@Wm1)@W2, bc2)
    k_cvt<<<(DIM * DIM / 8 + 255) / 256, 256, 0, stream>>>(W1, w1bf, DIM * DIM);
    k_head_prep<<<1, 256, 0, stream>>>(W2, b2, Wm1, bm1, Wm2, bm2, W2c, bc2);

    // 2-pass radix CSR build (rowptr/dinv/sort fused in pass 2)
    k_zero<<<(NBUCK + 255) / 256, 256, 0, stream>>>(gcount, NBUCK);
    k_p1hist<<<P1B, 256, 0, stream>>>(dst, gcount, blockbase);
    k_scanb<<<1, 256, 0, stream>>>(gcount, gbase);
    k_p1scatter<<<P1B, 256, 0, stream>>>(src, dst, gbase, blockbase, ebuf);
    k_p2<<<NBUCK, 256, 0, stream>>>(ebuf, gbase, rowptr, dinv, esrc);

    dim3 grid_d((N_NODES + 127) / 128, DIM / 128);
    const int GATHER_B = (N_NODES + 3) / 4;

    // layer 1: h' = dinv * (x@W1^T)   (fp32 x converted during LDS staging)
    k_gemm_mfma<true><<<grid_d, 256, 0, stream>>>(x, w1bf, nullptr, dinv, hbuf, N_NODES, DIM, DIM);
    // gather-1 + fused 5-wide transform: t' = dinv * ((b1 + dv*gather(h')) @ W2c^T)
    k_gather_t<<<GATHER_B, 256, 0, stream>>>(hbuf, rowptr, esrc, dinv, b1, W2c, tbuf);
    // layer-2 aggregation over 5-wide rows + bias
    k_gather_out<<<(N_NODES * 4 + 255) / 256, 256, 0, stream>>>(tbuf, rowptr, esrc, dinv, bc2, out);
}